// Round 5
// baseline (310.561 us; speedup 1.0000x reference)
//
#include <hip/hip_runtime.h>
#include <hip/hip_bf16.h>

#define N_NODES   50000
#define N_EDGES   800000
#define IN_DIM    64
#define HID       128
#define NUM_GRAPHS 256
#define NBUCK     196     // ceil(50000/256) chunks of 256 nodes

typedef __bf16 bf16x8 __attribute__((ext_vector_type(8)));
typedef unsigned short u16x8 __attribute__((ext_vector_type(8)));
typedef float f32x4 __attribute__((ext_vector_type(4)));

__device__ __forceinline__ float b2f(unsigned short u) {
    return __uint_as_float(((unsigned int)u) << 16);
}
__device__ __forceinline__ unsigned short f2b(float f) {
    unsigned int x = __float_as_uint(f);
    x = (x + 0x7fffu + ((x >> 16) & 1u)) >> 16;   // RNE
    return (unsigned short)x;
}

__global__ void diag_kernel(unsigned short* out, unsigned short pat) {
    out[threadIdx.x] = pat;
}

// ---------------- mega preprocess ----------------
// blocks 0..351: GIN weight reorder; 352..547: graph ranges + pool zero + deg zero;
// 548..579: head_w1 transpose -> w1t[n][k] bf16; 580: dtype probe
__global__ __launch_bounds__(256) void mega_pre_kernel(
    const unsigned short* __restrict__ x,
    const void* w0, const void* w1, const void* w2,
    const void* w3, const void* w4, const void* w5,
    unsigned short* __restrict__ wfbase,
    const int* __restrict__ batch, int* __restrict__ gstart,
    float* __restrict__ psum, unsigned int* __restrict__ pmax,
    const void* hw1, unsigned short* __restrict__ w1t,
    int* __restrict__ deg, int* __restrict__ flagp) {
    int b = blockIdx.x;
    int tid = threadIdx.x;

    if (b < 352) {
        __shared__ int cnt;
        if (tid == 0) cnt = 0;
        __syncthreads();
        unsigned short u = x[2 * tid];
        int e = (u >> 7) & 0xff;
        if (e <= 100 || e >= 140) atomicAdd(&cnt, 1);
        __syncthreads();
        int flag = cnt > 64;   // 1 = fp32, 0 = bf16

        int mat, boff;
        if (b < 32) { mat = 0; boff = b; }
        else { mat = 1 + (b - 32) / 64; boff = (b - 32) % 64; }
        const void* W = mat == 0 ? w0 : mat == 1 ? w1 : mat == 2 ? w2
                      : mat == 3 ? w3 : mat == 4 ? w4 : w5;
        int KC = (mat == 0) ? 2 : 4;
        int idx = boff * 256 + tid;
        int j  = idx & 7;
        int l  = (idx >> 3) & 63;
        int tc = idx >> 9;
        int c  = tc % KC;
        int t  = tc / KC;
        int k  = c * 32 + (l >> 4) * 8 + j;
        int n  = t * 16 + (l & 15);
        unsigned short v = flag ? f2b(((const float*)W)[k * 128 + n])
                                : ((const unsigned short*)W)[k * 128 + n];
        wfbase[mat * 16384 + idx] = v;
    } else if (b < 548) {
        int i = (b - 352) * 256 + tid;   // 0 .. 50175
        if (i < NUM_GRAPHS * HID) { psum[i] = 0.0f; pmax[i] = 0u; }
        deg[i] = 0;                      // deg sized 50176
        if (i >= N_NODES) return;
        int b1 = batch[i];
        int b0 = (i == 0) ? -1 : batch[i - 1];
        for (int g = b0 + 1; g <= b1; g++) gstart[g] = i;
        if (i == N_NODES - 1)
            for (int g = b1 + 1; g <= NUM_GRAPHS; g++) gstart[g] = N_NODES;
    } else if (b < 580) {
        // head_w1 transpose: w1t[n*256 + k] = hw1[k*128 + n], bf16
        __shared__ int cnt;
        if (tid == 0) cnt = 0;
        __syncthreads();
        unsigned short u = x[2 * tid];
        int e = (u >> 7) & 0xff;
        if (e <= 100 || e >= 140) atomicAdd(&cnt, 1);
        __syncthreads();
        int flag = cnt > 64;
        int base = (b - 548) * 1024;
#pragma unroll
        for (int j = 0; j < 4; j++) {
            int idx = base + j * 256 + tid;   // [0, 32768)
            int n = idx >> 8;
            int k = idx & 255;
            unsigned short v = flag ? f2b(((const float*)hw1)[k * 128 + n])
                                    : ((const unsigned short*)hw1)[k * 128 + n];
            w1t[idx] = v;
        }
    } else {
        __shared__ int cnt;
        if (tid == 0) cnt = 0;
        __syncthreads();
        int c = 0;
        for (int j = 0; j < 16; j++) {
            unsigned short u = x[2 * (tid * 16 + j)];
            int e = (u >> 7) & 0xff;
            if (e <= 100 || e >= 140) c++;
        }
        atomicAdd(&cnt, c);
        __syncthreads();
        if (tid == 0) *flagp = (cnt > 1024) ? 1 : 0;
    }
}

// ---------------- direct CSR build ----------------
// deg count: one thread per edge, global atomics (L2-side, ~16-way avg contention)
__global__ __launch_bounds__(1024) void deg_kernel(const int* __restrict__ dst,
        int* __restrict__ deg) {
    int e = blockIdx.x * 1024 + threadIdx.x;
    if (e < N_EDGES) atomicAdd(&deg[dst[e]], 1);
}

// per-chunk sums: part[b] = sum(deg[b*256 .. b*256+255])
__global__ __launch_bounds__(256) void part_kernel(const int* __restrict__ deg,
        int* __restrict__ part) {
    __shared__ int red[256];
    int b = blockIdx.x, t = threadIdx.x;
    red[t] = deg[b * 256 + t];          // deg sized 50176: tail reads zeros
    __syncthreads();
    for (int s = 128; s > 0; s >>= 1) {
        if (t < s) red[t] += red[t + s];
        __syncthreads();
    }
    if (t == 0) part[b] = red[0];
}

// offsets: each block redundantly scans part[196] + local scan of its deg chunk
__global__ __launch_bounds__(256) void off_kernel(const int* __restrict__ deg,
        const int* __restrict__ part, int* __restrict__ off, int* __restrict__ cur) {
    __shared__ int sc[256];
    __shared__ int ls[256];
    int b = blockIdx.x, t = threadIdx.x;
    sc[t] = (t < NBUCK) ? part[t] : 0;
    __syncthreads();
    for (int d = 1; d < 256; d <<= 1) {
        int v = (t >= d) ? sc[t - d] : 0;
        __syncthreads();
        sc[t] += v;
        __syncthreads();
    }
    int base = (b == 0) ? 0 : sc[b - 1];
    int dv = deg[b * 256 + t];
    ls[t] = dv;
    __syncthreads();
    for (int d = 1; d < 256; d <<= 1) {
        int v = (t >= d) ? ls[t - d] : 0;
        __syncthreads();
        ls[t] += v;
        __syncthreads();
    }
    int node = b * 256 + t;
    int o = base + ls[t] - dv;
    if (node < N_NODES) { off[node] = o; cur[node] = o; }
    if (b == 0 && t == 0) off[N_NODES] = N_EDGES;
}

// scatter: one thread per edge; csr position via atomic cursor
__global__ __launch_bounds__(1024) void scatter_kernel(const int* __restrict__ src,
        const int* __restrict__ dst, int* __restrict__ cur,
        unsigned short* __restrict__ csr) {
    int e = blockIdx.x * 1024 + threadIdx.x;
    if (e < N_EDGES) {
        int d = dst[e];
        int p = atomicAdd(&cur[d], 1);
        csr[p] = (unsigned short)src[e];
    }
}

// ---------------- fused gather + GIN MLP (R3 barrier-free version) ----------------
// One block = 64 output rows, 4 waves. Each wave gathers its own 16 rows
// (4 nodes/pass, 16 lanes each) into wave-private rows of lds_hi (z tile),
// then runs the MFMA body reading A-fragments from LDS. No barrier needed:
// rows are wave-private; fast waves slide past slow ones (degree variance).
// POOL=true: in-block mean/max pooling (layer 2), no h store.
template <int K1, bool POOL, bool FROMX>
__global__ __launch_bounds__(256, 3) void fused_gin_kernel(
    const void* __restrict__ X,
    const int* __restrict__ off, const unsigned short* __restrict__ csr,
    const unsigned short* __restrict__ Wf1, const void* __restrict__ bias1,
    const unsigned short* __restrict__ Wf2, const void* __restrict__ bias2,
    unsigned short* __restrict__ Out, int M, const int* __restrict__ flagp,
    const int* __restrict__ batch, float* __restrict__ psum,
    unsigned int* __restrict__ pmax) {
    constexpr int KC1 = K1 / 32;
    __shared__ __align__(16) unsigned short lds_hi[64 * 136];
    __shared__ __align__(16) unsigned short lds_lo[64 * 136];
    __shared__ int batch_lds[64];

    int flag = *flagp;
    int wave = threadIdx.x >> 6;
    int lane = threadIdx.x & 63;
    int m_ = lane & 15;
    int q  = lane >> 4;

    if constexpr (POOL) {
        if (threadIdx.x < 64) {
            int gr = blockIdx.x * 64 + threadIdx.x;
            batch_lds[threadIdx.x] = gr < M ? batch[gr] : -1;
        }
    }

    // ================= gather phase (wave-private rows) =================
    int np = lane >> 4;      // node within pass (0..3)
    int l  = lane & 15;      // feat-lane within node
#pragma unroll 1
    for (int p = 0; p < 4; p++) {
        int nl = wave * 16 + p * 4 + np;           // node_local 0..63
        int node = blockIdx.x * 64 + nl;
        int nodec = node < M ? node : (M - 1);
        int s = off[nodec], e = off[nodec + 1];
        if constexpr (FROMX) {
            float a0, a1, a2, a3;
            float b0 = 0.f, b1 = 0.f, b2 = 0.f, b3 = 0.f;
            float c0 = 0.f, c1 = 0.f, c2 = 0.f, c3 = 0.f;
            float d0 = 0.f, d1 = 0.f, d2 = 0.f, d3 = 0.f;
            if (flag) {
                const float4* xp = (const float4*)X;
                float4 u = xp[(size_t)nodec * 16 + l];
                a0 = u.x; a1 = u.y; a2 = u.z; a3 = u.w;
                int i = s;
                for (; i + 3 < e; i += 4) {
                    float4 v0 = xp[(size_t)csr[i] * 16 + l];
                    float4 v1 = xp[(size_t)csr[i + 1] * 16 + l];
                    float4 v2 = xp[(size_t)csr[i + 2] * 16 + l];
                    float4 v3 = xp[(size_t)csr[i + 3] * 16 + l];
                    a0 += v0.x; a1 += v0.y; a2 += v0.z; a3 += v0.w;
                    b0 += v1.x; b1 += v1.y; b2 += v1.z; b3 += v1.w;
                    c0 += v2.x; c1 += v2.y; c2 += v2.z; c3 += v2.w;
                    d0 += v3.x; d1 += v3.y; d2 += v3.z; d3 += v3.w;
                }
                for (; i < e; i++) {
                    float4 v = xp[(size_t)csr[i] * 16 + l];
                    a0 += v.x; a1 += v.y; a2 += v.z; a3 += v.w;
                }
            } else {
                const ushort4* xp = (const ushort4*)X;
                ushort4 u = xp[(size_t)nodec * 16 + l];
                a0 = b2f(u.x); a1 = b2f(u.y); a2 = b2f(u.z); a3 = b2f(u.w);
                int i = s;
                for (; i + 3 < e; i += 4) {
                    ushort4 v0 = xp[(size_t)csr[i] * 16 + l];
                    ushort4 v1 = xp[(size_t)csr[i + 1] * 16 + l];
                    ushort4 v2 = xp[(size_t)csr[i + 2] * 16 + l];
                    ushort4 v3 = xp[(size_t)csr[i + 3] * 16 + l];
                    a0 += b2f(v0.x); a1 += b2f(v0.y); a2 += b2f(v0.z); a3 += b2f(v0.w);
                    b0 += b2f(v1.x); b1 += b2f(v1.y); b2 += b2f(v1.z); b3 += b2f(v1.w);
                    c0 += b2f(v2.x); c1 += b2f(v2.y); c2 += b2f(v2.z); c3 += b2f(v2.w);
                    d0 += b2f(v3.x); d1 += b2f(v3.y); d2 += b2f(v3.z); d3 += b2f(v3.w);
                }
                for (; i < e; i++) {
                    ushort4 v = xp[(size_t)csr[i] * 16 + l];
                    a0 += b2f(v.x); a1 += b2f(v.y); a2 += b2f(v.z); a3 += b2f(v.w);
                }
            }
            ushort4 o;
            o.x = f2b(a0 + b0 + c0 + d0);
            o.y = f2b(a1 + b1 + c1 + d1);
            o.z = f2b(a2 + b2 + c2 + d2);
            o.w = f2b(a3 + b3 + c3 + d3);
            *reinterpret_cast<ushort4*>(&lds_hi[nl * 136 + l * 4]) = o;
        } else {
            const u16x8* hp = (const u16x8*)X;
            u16x8 u = hp[(size_t)nodec * 16 + l];
            float a[8], b[8], c[8], d[8];
#pragma unroll
            for (int j = 0; j < 8; j++) { a[j] = b2f(u[j]); b[j] = 0.f; c[j] = 0.f; d[j] = 0.f; }
            int i = s;
            for (; i + 3 < e; i += 4) {
                u16x8 v0 = hp[(size_t)csr[i] * 16 + l];
                u16x8 v1 = hp[(size_t)csr[i + 1] * 16 + l];
                u16x8 v2 = hp[(size_t)csr[i + 2] * 16 + l];
                u16x8 v3 = hp[(size_t)csr[i + 3] * 16 + l];
#pragma unroll
                for (int j = 0; j < 8; j++) {
                    a[j] += b2f(v0[j]); b[j] += b2f(v1[j]);
                    c[j] += b2f(v2[j]); d[j] += b2f(v3[j]);
                }
            }
            for (; i < e; i++) {
                u16x8 v = hp[(size_t)csr[i] * 16 + l];
#pragma unroll
                for (int j = 0; j < 8; j++) a[j] += b2f(v[j]);
            }
            u16x8 o;
#pragma unroll
            for (int j = 0; j < 8; j++) o[j] = f2b(a[j] + b[j] + c[j] + d[j]);
            *reinterpret_cast<u16x8*>(&lds_hi[nl * 136 + l * 8]) = o;
        }
    }

    // ================= MFMA phase (A-frags from LDS) =================
    const unsigned short* wfl1 = Wf1 + lane * 8;
    const unsigned short* wfl2 = Wf2 + lane * 8;
    const unsigned short* zlds = &lds_hi[(wave * 16 + m_) * 136 + q * 8];

    bf16x8 afrag[KC1];
#pragma unroll
    for (int c = 0; c < KC1; c++)
        afrag[c] = *reinterpret_cast<const bf16x8*>(zlds + c * 32);

    float b1v[8], b2v[8];
#pragma unroll
    for (int t = 0; t < 8; t++) {
        int col = t * 16 + m_;
        b1v[t] = flag ? ((const float*)bias1)[col]
                      : b2f(((const unsigned short*)bias1)[col]);
        b2v[t] = flag ? ((const float*)bias2)[col]
                      : b2f(((const unsigned short*)bias2)[col]);
    }

    f32x4 acc[8];
#pragma unroll
    for (int t = 0; t < 8; t++) acc[t] = (f32x4)(0.0f);

    // phase 1: mid = Z @ W1, weights double-buffered 8 fragments wide
    {
        bf16x8 wb[8], wn[8];
#pragma unroll
        for (int t = 0; t < 8; t++)
            wb[t] = *reinterpret_cast<const bf16x8*>(wfl1 + ((t * KC1 + 0) << 9));
#pragma unroll
        for (int c = 0; c < KC1; c++) {
            if (c + 1 < KC1) {
#pragma unroll
                for (int t = 0; t < 8; t++)
                    wn[t] = *reinterpret_cast<const bf16x8*>(wfl1 + ((t * KC1 + c + 1) << 9));
            }
#pragma unroll
            for (int t = 0; t < 8; t++)
                acc[t] = __builtin_amdgcn_mfma_f32_16x16x32_bf16(afrag[c], wb[t], acc[t], 0, 0, 0);
            if (c + 1 < KC1) {
#pragma unroll
                for (int t = 0; t < 8; t++) wb[t] = wn[t];
            }
        }
    }

    // epilogue 1: +b1, relu, hi/lo split -> LDS
#pragma unroll
    for (int r = 0; r < 4; r++) {
        int lr = wave * 16 + q * 4 + r;
#pragma unroll
        for (int t = 0; t < 8; t++) {
            int col = t * 16 + m_;
            float v = acc[t][r] + b1v[t];
            v = v > 0.0f ? v : 0.0f;
            unsigned short hb = f2b(v);
            lds_hi[lr * 136 + col] = hb;
            lds_lo[lr * 136 + col] = f2b(v - b2f(hb));
        }
    }

#pragma unroll
    for (int t = 0; t < 8; t++) acc[t] = (f32x4)(0.0f);

    // phase 2: h = mid @ W2 (hi/lo from LDS), weights double-buffered
    {
        int lr2 = wave * 16 + m_;
        const unsigned short* hibase = &lds_hi[lr2 * 136 + q * 8];
        const unsigned short* lobase = &lds_lo[lr2 * 136 + q * 8];
        bf16x8 wb[8], wn[8];
#pragma unroll
        for (int t = 0; t < 8; t++)
            wb[t] = *reinterpret_cast<const bf16x8*>(wfl2 + ((t * 4 + 0) << 9));
#pragma unroll
        for (int c = 0; c < 4; c++) {
            if (c < 3) {
#pragma unroll
                for (int t = 0; t < 8; t++)
                    wn[t] = *reinterpret_cast<const bf16x8*>(wfl2 + ((t * 4 + c + 1) << 9));
            }
            bf16x8 ahi = *reinterpret_cast<const bf16x8*>(hibase + c * 32);
            bf16x8 alo = *reinterpret_cast<const bf16x8*>(lobase + c * 32);
#pragma unroll
            for (int t = 0; t < 8; t++) {
                acc[t] = __builtin_amdgcn_mfma_f32_16x16x32_bf16(ahi, wb[t], acc[t], 0, 0, 0);
                acc[t] = __builtin_amdgcn_mfma_f32_16x16x32_bf16(alo, wb[t], acc[t], 0, 0, 0);
            }
            if (c < 3) {
#pragma unroll
                for (int t = 0; t < 8; t++) wb[t] = wn[t];
            }
        }
    }

    // epilogue 2
#pragma unroll
    for (int r = 0; r < 4; r++) {
        int lr = wave * 16 + q * 4 + r;
        int orow = blockIdx.x * 64 + lr;
#pragma unroll
        for (int t = 0; t < 8; t++) {
            int col = t * 16 + m_;
            float v = acc[t][r] + b2v[t];
            v = v > 0.0f ? v : 0.0f;
            if constexpr (POOL) {
                lds_hi[lr * 136 + col] = f2b(v);   // safe: own rows' phase-2 reads done
            } else {
                if (orow < M) Out[(size_t)orow * HID + col] = f2b(v);
            }
        }
    }

    if constexpr (POOL) {
        __syncthreads();
        int f = threadIdx.x;
        if (f < HID) {
            int cur = -1;
            float sum = 0.0f, mx = 0.0f;
            for (int rrow = 0; rrow < 64; rrow++) {
                int g = batch_lds[rrow];
                if (g < 0) break;   // tail padding
                float v = b2f(lds_hi[rrow * 136 + f]);
                if (g == cur) {
                    sum += v;
                    mx = fmaxf(mx, v);
                } else {
                    if (cur >= 0) {
                        atomicAdd(&psum[cur * HID + f], sum);
                        atomicMax(&pmax[cur * HID + f], __float_as_uint(mx));
                    }
                    cur = g; sum = v; mx = v;
                }
            }
            if (cur >= 0) {
                atomicAdd(&psum[cur * HID + f], sum);
                atomicMax(&pmax[cur * HID + f], __float_as_uint(mx));
            }
        }
    }
}

// ---------------- head: w1t[n][k] bf16 rows -> vectorized, unrolled dot ----------------
__global__ __launch_bounds__(128) void head_kernel(
    const float* __restrict__ psum, const unsigned int* __restrict__ pmax,
    const int* __restrict__ gstart,
    const unsigned short* __restrict__ w1t,
    const void* __restrict__ b1, const void* __restrict__ w2,
    const void* __restrict__ b2,
    void* __restrict__ out, const int* __restrict__ flagp) {
    int g = blockIdx.x;
    int n = threadIdx.x;
    int flag = *flagp;
    __shared__ float repr[2 * HID];
    __shared__ float red[HID];

    float c = (float)(gstart[g + 1] - gstart[g]);
    float inv = 1.0f / fmaxf(c, 1.0f);
    repr[n]       = psum[g * HID + n] * inv;
    repr[HID + n] = __uint_as_float(pmax[g * HID + n]);
    __syncthreads();

    const u16x8* wp = (const u16x8*)(w1t + n * 256);
    float a0 = 0.f, a1 = 0.f, a2 = 0.f, a3 = 0.f;
#pragma unroll
    for (int c8 = 0; c8 < 32; c8 += 4) {
        u16x8 w0 = wp[c8 + 0];
        u16x8 w1 = wp[c8 + 1];
        u16x8 w2v = wp[c8 + 2];
        u16x8 w3 = wp[c8 + 3];
#pragma unroll
        for (int j = 0; j < 8; j++) {
            a0 += repr[(c8 + 0) * 8 + j] * b2f(w0[j]);
            a1 += repr[(c8 + 1) * 8 + j] * b2f(w1[j]);
            a2 += repr[(c8 + 2) * 8 + j] * b2f(w2v[j]);
            a3 += repr[(c8 + 3) * 8 + j] * b2f(w3[j]);
        }
    }
    float b1v = flag ? ((const float*)b1)[n] : b2f(((const unsigned short*)b1)[n]);
    float acc = a0 + a1 + a2 + a3 + b1v;
    acc = fmaxf(acc, 0.0f);

    float w2s = flag ? ((const float*)w2)[n] : b2f(((const unsigned short*)w2)[n]);
    red[n] = acc * w2s;
    __syncthreads();
    for (int s = 64; s > 0; s >>= 1) {
        if (n < s) red[n] += red[n + s];
        __syncthreads();
    }
    if (n == 0) {
        float b2v = flag ? ((const float*)b2)[0] : b2f(((const unsigned short*)b2)[0]);
        float logit = red[0] + b2v;
        float sv = 1.0f / (1.0f + expf(-logit));
        if (flag) ((float*)out)[g] = sv;
        else      ((unsigned short*)out)[g] = f2b(sv);
    }
}

extern "C" void kernel_launch(void* const* d_in, const int* in_sizes, int n_in,
                              void* d_out, int out_size, void* d_ws, size_t ws_size,
                              hipStream_t stream) {
    const int* edge = (const int*)d_in[1];
    const int* srcv = edge;
    const int* dstv = edge + N_EDGES;
    const int* batch = (const int*)d_in[2];

    char* ws = (char*)d_ws;
    unsigned short* A = (unsigned short*)ws;               // 12.8 MB bf16 h (even)
    unsigned short* B = (unsigned short*)(ws + 12800000);  // 12.8 MB bf16 h (odd)
    int* deg  = (int*)(ws + 25600000);                     // 50176 ints (200.7 KB)
    int* part = (int*)(ws + 25800704);                     // 196 ints
    int* cur  = (int*)(ws + 25801728);                     // 50000 ints (200 KB)
    unsigned short* csr = (unsigned short*)(ws + 32100000);// 1.6 MB
    int* off    = (int*)(ws + 33700000);                   // 50001 ints
    unsigned short* wfbase = (unsigned short*)(ws + 33904000);  // 6 x 32 KB
    float* psum  = (float*)(ws + 34100608);                // 128 KB
    unsigned int* pmax = (unsigned int*)(ws + 34231680);   // 128 KB
    int* gstart  = (int*)(ws + 34363776);                  // 2 KB
    int* flagp   = (int*)(ws + 34365824);
    unsigned short* w1t = (unsigned short*)(ws + 34366848); // 64 KB

    const size_t NEED = 34500000;
    if (ws_size < NEED) {
        unsigned int k = 0;
        while ((((size_t)1) << (k + 1)) <= ws_size && k < 62) k++;
        diag_kernel<<<1, 256, 0, stream>>>((unsigned short*)d_out,
                                           (unsigned short)(0x4000 | (k & 63)));
        return;
    }

    mega_pre_kernel<<<581, 256, 0, stream>>>(
        (const unsigned short*)d_in[0],
        d_in[3], d_in[5], d_in[7], d_in[9], d_in[11], d_in[13], wfbase,
        batch, gstart, psum, pmax, d_in[15], w1t, deg, flagp);

    // direct CSR build: deg count -> chunk sums -> offsets -> scatter
    const int EB = (N_EDGES + 1023) / 1024;   // 782
    deg_kernel<<<EB, 1024, 0, stream>>>(dstv, deg);
    part_kernel<<<NBUCK, 256, 0, stream>>>(deg, part);
    off_kernel<<<NBUCK, 256, 0, stream>>>(deg, part, off, cur);
    scatter_kernel<<<EB, 1024, 0, stream>>>(srcv, dstv, cur, csr);

    const int GEMM_GRID = (N_NODES + 63) / 64;   // 782

    // layer 0: x -> A (fused gather_x + MLP0)
    fused_gin_kernel<64, false, true><<<GEMM_GRID, 256, 0, stream>>>(
        d_in[0], off, csr,
        wfbase + 0 * 16384, d_in[4], wfbase + 1 * 16384, d_in[6],
        A, N_NODES, flagp, batch, psum, pmax);

    // layer 1: A -> B (fused gather128 + MLP1)
    fused_gin_kernel<128, false, false><<<GEMM_GRID, 256, 0, stream>>>(
        A, off, csr,
        wfbase + 2 * 16384, d_in[8], wfbase + 3 * 16384, d_in[10],
        B, N_NODES, flagp, batch, psum, pmax);

    // layer 2: B -> pooled directly (fused gather128 + MLP2 + pool)
    fused_gin_kernel<128, true, false><<<GEMM_GRID, 256, 0, stream>>>(
        B, off, csr,
        wfbase + 4 * 16384, d_in[12], wfbase + 5 * 16384, d_in[14],
        A /*unused*/, N_NODES, flagp, batch, psum, pmax);

    // head
    head_kernel<<<NUM_GRAPHS, 128, 0, stream>>>(psum, pmax, gstart, w1t,
                                                d_in[16], d_in[17], d_in[18],
                                                d_out, flagp);
}

// Round 6
// 261.421 us; speedup vs baseline: 1.1880x; 1.1880x over previous
//
#include <hip/hip_runtime.h>
#include <hip/hip_bf16.h>

#define N_NODES   50000
#define N_EDGES   800000
#define IN_DIM    64
#define HID       128
#define NUM_GRAPHS 256
#define NBUCK     196     // ceil(50000/256) buckets of 256 nodes
#define BCAP      8192    // fixed ebuf capacity per bucket (avg fill 4082)

typedef __bf16 bf16x8 __attribute__((ext_vector_type(8)));
typedef unsigned short u16x8 __attribute__((ext_vector_type(8)));
typedef float f32x4 __attribute__((ext_vector_type(4)));

__device__ __forceinline__ float b2f(unsigned short u) {
    return __uint_as_float(((unsigned int)u) << 16);
}
__device__ __forceinline__ unsigned short f2b(float f) {
    unsigned int x = __float_as_uint(f);
    x = (x + 0x7fffu + ((x >> 16) & 1u)) >> 16;   // RNE
    return (unsigned short)x;
}

__global__ void diag_kernel(unsigned short* out, unsigned short pat) {
    out[threadIdx.x] = pat;
}

// ---------------- mega preprocess ----------------
// blocks 0..351: GIN weight reorder; 352..547: graph ranges + pool zero;
// 548..579: head_w1 transpose -> w1t[n][k] bf16; 580: dtype probe + bucket cursor init
__global__ __launch_bounds__(256) void mega_pre_kernel(
    const unsigned short* __restrict__ x,
    const void* w0, const void* w1, const void* w2,
    const void* w3, const void* w4, const void* w5,
    unsigned short* __restrict__ wfbase,
    const int* __restrict__ batch, int* __restrict__ gstart,
    float* __restrict__ psum, unsigned int* __restrict__ pmax,
    const void* hw1, unsigned short* __restrict__ w1t,
    int* __restrict__ bcursor, int* __restrict__ flagp) {
    int b = blockIdx.x;
    int tid = threadIdx.x;

    if (b < 352) {
        __shared__ int cnt;
        if (tid == 0) cnt = 0;
        __syncthreads();
        unsigned short u = x[2 * tid];
        int e = (u >> 7) & 0xff;
        if (e <= 100 || e >= 140) atomicAdd(&cnt, 1);
        __syncthreads();
        int flag = cnt > 64;   // 1 = fp32, 0 = bf16

        int mat, boff;
        if (b < 32) { mat = 0; boff = b; }
        else { mat = 1 + (b - 32) / 64; boff = (b - 32) % 64; }
        const void* W = mat == 0 ? w0 : mat == 1 ? w1 : mat == 2 ? w2
                      : mat == 3 ? w3 : mat == 4 ? w4 : w5;
        int KC = (mat == 0) ? 2 : 4;
        int idx = boff * 256 + tid;
        int j  = idx & 7;
        int l  = (idx >> 3) & 63;
        int tc = idx >> 9;
        int c  = tc % KC;
        int t  = tc / KC;
        int k  = c * 32 + (l >> 4) * 8 + j;
        int n  = t * 16 + (l & 15);
        unsigned short v = flag ? f2b(((const float*)W)[k * 128 + n])
                                : ((const unsigned short*)W)[k * 128 + n];
        wfbase[mat * 16384 + idx] = v;
    } else if (b < 548) {
        int i = (b - 352) * 256 + tid;
        if (i < NUM_GRAPHS * HID) { psum[i] = 0.0f; pmax[i] = 0u; }
        if (i >= N_NODES) return;
        int b1 = batch[i];
        int b0 = (i == 0) ? -1 : batch[i - 1];
        for (int g = b0 + 1; g <= b1; g++) gstart[g] = i;
        if (i == N_NODES - 1)
            for (int g = b1 + 1; g <= NUM_GRAPHS; g++) gstart[g] = N_NODES;
    } else if (b < 580) {
        // head_w1 transpose: w1t[n*256 + k] = hw1[k*128 + n], bf16
        __shared__ int cnt;
        if (tid == 0) cnt = 0;
        __syncthreads();
        unsigned short u = x[2 * tid];
        int e = (u >> 7) & 0xff;
        if (e <= 100 || e >= 140) atomicAdd(&cnt, 1);
        __syncthreads();
        int flag = cnt > 64;
        int base = (b - 548) * 1024;
#pragma unroll
        for (int j = 0; j < 4; j++) {
            int idx = base + j * 256 + tid;   // [0, 32768)
            int n = idx >> 8;
            int k = idx & 255;
            unsigned short v = flag ? f2b(((const float*)hw1)[k * 128 + n])
                                    : ((const unsigned short*)hw1)[k * 128 + n];
            w1t[idx] = v;
        }
    } else {
        if (tid < NBUCK) bcursor[tid] = tid * BCAP;
        __shared__ int cnt;
        if (tid == 0) cnt = 0;
        __syncthreads();
        int c = 0;
        for (int j = 0; j < 16; j++) {
            unsigned short u = x[2 * (tid * 16 + j)];
            int e = (u >> 7) & 0xff;
            if (e <= 100 || e >= 140) c++;
        }
        atomicAdd(&cnt, c);
        __syncthreads();
        if (tid == 0) *flagp = (cnt > 1024) ? 1 : 0;
    }
}

// ---------------- CSR build: scatter into fixed-capacity bucket regions ----------------
__global__ __launch_bounds__(1024) void bscatter_kernel(const int* __restrict__ src,
        const int* __restrict__ dst, int* __restrict__ bcursor,
        unsigned int* __restrict__ ebuf) {
    __shared__ int lcnt[NBUCK];
    __shared__ int lbase[NBUCK];
    __shared__ int lcur[NBUCK];
    int tid = threadIdx.x;
    if (tid < NBUCK) lcnt[tid] = 0;
    __syncthreads();
    int e0 = blockIdx.x * 4096;
    int d[4], s[4];
#pragma unroll
    for (int k = 0; k < 4; k++) {
        int e = e0 + k * 1024 + tid;
        if (e < N_EDGES) {
            d[k] = dst[e]; s[k] = src[e];
            atomicAdd(&lcnt[d[k] >> 8], 1);
        } else d[k] = -1;
    }
    __syncthreads();
    if (tid < NBUCK) {
        int c = lcnt[tid];
        lbase[tid] = c ? atomicAdd(&bcursor[tid], c) : 0;
        lcur[tid] = 0;
    }
    __syncthreads();
#pragma unroll
    for (int k = 0; k < 4; k++) {
        if (d[k] >= 0) {
            int b = d[k] >> 8;
            int p = lbase[b] + atomicAdd(&lcur[b], 1);
            ebuf[p] = ((unsigned int)(d[k] & 255) << 16) | (unsigned int)s[k];
        }
    }
}

// per-bucket counting sort -> compact off + csr; bucket counts/bases derived
// from final cursors via a redundant in-block 196-scan (replaces bscan pass).
__global__ __launch_bounds__(256) void bsort_kernel(const unsigned int* __restrict__ ebuf,
        const int* __restrict__ bcursor, int* __restrict__ off,
        unsigned short* __restrict__ csr) {
    __shared__ int cntA[256];
    __shared__ int sc[256];
    __shared__ int lcnt[256];
    __shared__ int lcur[256];
    int b = blockIdx.x, tid = threadIdx.x;

    int v = (tid < NBUCK) ? (bcursor[tid] - tid * BCAP) : 0;
    cntA[tid] = v;
    sc[tid] = v;
    __syncthreads();
    for (int d = 1; d < 256; d <<= 1) {
        int t = (tid >= d) ? sc[tid - d] : 0;
        __syncthreads();
        sc[tid] += t;
        __syncthreads();
    }
    int base = sc[b] - cntA[b];   // exclusive prefix for this bucket
    int cnt  = cntA[b];
    int ebase = b * BCAP;
    __syncthreads();

    lcnt[tid] = 0;
    __syncthreads();
    for (int i = tid; i < cnt; i += 256)
        atomicAdd(&lcnt[ebuf[ebase + i] >> 16], 1);
    __syncthreads();
    int v2 = lcnt[tid];
    sc[tid] = v2;
    __syncthreads();
    for (int d = 1; d < 256; d <<= 1) {
        int t = (tid >= d) ? sc[tid - d] : 0;
        __syncthreads();
        sc[tid] += t;
        __syncthreads();
    }
    int excl = sc[tid] - v2;
    lcur[tid] = excl;
    int node = b * 256 + tid;
    if (node < N_NODES) off[node] = base + excl;
    if (b == 0 && tid == 0) off[N_NODES] = N_EDGES;
    __syncthreads();
    for (int i = tid; i < cnt; i += 256) {
        unsigned int ev = ebuf[ebase + i];
        int p = atomicAdd(&lcur[ev >> 16], 1);
        csr[base + p] = (unsigned short)(ev & 0xffffu);
    }
}

// ---------------- fused gather + GIN MLP (R6: 1-wave blocks) ----------------
// One block = ONE WAVE = 16 output rows (grid 3125, 50000 = 16*3125 exact).
// The wave gathers its 16 rows (4 passes x 4 nodes x 16 lanes) into lds_hi
// (z tile), then runs the same MFMA body as R3. Zero barriers in non-POOL
// path; finished waves free their block slot immediately (no straggler
// coupling across waves). POOL=true: per-wave 16-row pooling.
template <int K1, bool POOL, bool FROMX>
__global__ __launch_bounds__(64, 6) void fused_gin_kernel(
    const void* __restrict__ X,
    const int* __restrict__ off, const unsigned short* __restrict__ csr,
    const unsigned short* __restrict__ Wf1, const void* __restrict__ bias1,
    const unsigned short* __restrict__ Wf2, const void* __restrict__ bias2,
    unsigned short* __restrict__ Out, int M, const int* __restrict__ flagp,
    const int* __restrict__ batch, float* __restrict__ psum,
    unsigned int* __restrict__ pmax) {
    constexpr int KC1 = K1 / 32;
    __shared__ __align__(16) unsigned short lds_hi[16 * 136];
    __shared__ __align__(16) unsigned short lds_lo[16 * 136];
    __shared__ int batch_lds[16];

    int flag = *flagp;
    int lane = threadIdx.x;        // 0..63 (one wave)
    int m_ = lane & 15;
    int q  = lane >> 4;

    if constexpr (POOL) {
        if (lane < 16) batch_lds[lane] = batch[blockIdx.x * 16 + lane];
    }

    // ================= gather phase (16 rows, 4 passes) =================
    int np = lane >> 4;      // node within pass (0..3)
    int l  = lane & 15;      // feat-lane within node
#pragma unroll 1
    for (int p = 0; p < 4; p++) {
        int nl = p * 4 + np;                       // node_local 0..15
        int node = blockIdx.x * 16 + nl;           // always < N_NODES (exact grid)
        int s = off[node], e = off[node + 1];
        if constexpr (FROMX) {
            float a0, a1, a2, a3;
            float b0 = 0.f, b1 = 0.f, b2 = 0.f, b3 = 0.f;
            float c0 = 0.f, c1 = 0.f, c2 = 0.f, c3 = 0.f;
            float d0 = 0.f, d1 = 0.f, d2 = 0.f, d3 = 0.f;
            if (flag) {
                const float4* xp = (const float4*)X;
                float4 u = xp[(size_t)node * 16 + l];
                a0 = u.x; a1 = u.y; a2 = u.z; a3 = u.w;
                int i = s;
                for (; i + 3 < e; i += 4) {
                    float4 v0 = xp[(size_t)csr[i] * 16 + l];
                    float4 v1 = xp[(size_t)csr[i + 1] * 16 + l];
                    float4 v2 = xp[(size_t)csr[i + 2] * 16 + l];
                    float4 v3 = xp[(size_t)csr[i + 3] * 16 + l];
                    a0 += v0.x; a1 += v0.y; a2 += v0.z; a3 += v0.w;
                    b0 += v1.x; b1 += v1.y; b2 += v1.z; b3 += v1.w;
                    c0 += v2.x; c1 += v2.y; c2 += v2.z; c3 += v2.w;
                    d0 += v3.x; d1 += v3.y; d2 += v3.z; d3 += v3.w;
                }
                for (; i < e; i++) {
                    float4 v = xp[(size_t)csr[i] * 16 + l];
                    a0 += v.x; a1 += v.y; a2 += v.z; a3 += v.w;
                }
            } else {
                const ushort4* xp = (const ushort4*)X;
                ushort4 u = xp[(size_t)node * 16 + l];
                a0 = b2f(u.x); a1 = b2f(u.y); a2 = b2f(u.z); a3 = b2f(u.w);
                int i = s;
                for (; i + 3 < e; i += 4) {
                    ushort4 v0 = xp[(size_t)csr[i] * 16 + l];
                    ushort4 v1 = xp[(size_t)csr[i + 1] * 16 + l];
                    ushort4 v2 = xp[(size_t)csr[i + 2] * 16 + l];
                    ushort4 v3 = xp[(size_t)csr[i + 3] * 16 + l];
                    a0 += b2f(v0.x); a1 += b2f(v0.y); a2 += b2f(v0.z); a3 += b2f(v0.w);
                    b0 += b2f(v1.x); b1 += b2f(v1.y); b2 += b2f(v1.z); b3 += b2f(v1.w);
                    c0 += b2f(v2.x); c1 += b2f(v2.y); c2 += b2f(v2.z); c3 += b2f(v2.w);
                    d0 += b2f(v3.x); d1 += b2f(v3.y); d2 += b2f(v3.z); d3 += b2f(v3.w);
                }
                for (; i < e; i++) {
                    ushort4 v = xp[(size_t)csr[i] * 16 + l];
                    a0 += b2f(v.x); a1 += b2f(v.y); a2 += b2f(v.z); a3 += b2f(v.w);
                }
            }
            ushort4 o;
            o.x = f2b(a0 + b0 + c0 + d0);
            o.y = f2b(a1 + b1 + c1 + d1);
            o.z = f2b(a2 + b2 + c2 + d2);
            o.w = f2b(a3 + b3 + c3 + d3);
            *reinterpret_cast<ushort4*>(&lds_hi[nl * 136 + l * 4]) = o;
        } else {
            const u16x8* hp = (const u16x8*)X;
            u16x8 u = hp[(size_t)node * 16 + l];
            float a[8], b[8], c[8], d[8];
#pragma unroll
            for (int j = 0; j < 8; j++) { a[j] = b2f(u[j]); b[j] = 0.f; c[j] = 0.f; d[j] = 0.f; }
            int i = s;
            for (; i + 3 < e; i += 4) {
                u16x8 v0 = hp[(size_t)csr[i] * 16 + l];
                u16x8 v1 = hp[(size_t)csr[i + 1] * 16 + l];
                u16x8 v2 = hp[(size_t)csr[i + 2] * 16 + l];
                u16x8 v3 = hp[(size_t)csr[i + 3] * 16 + l];
#pragma unroll
                for (int j = 0; j < 8; j++) {
                    a[j] += b2f(v0[j]); b[j] += b2f(v1[j]);
                    c[j] += b2f(v2[j]); d[j] += b2f(v3[j]);
                }
            }
            for (; i < e; i++) {
                u16x8 v = hp[(size_t)csr[i] * 16 + l];
#pragma unroll
                for (int j = 0; j < 8; j++) a[j] += b2f(v[j]);
            }
            u16x8 o;
#pragma unroll
            for (int j = 0; j < 8; j++) o[j] = f2b(a[j] + b[j] + c[j] + d[j]);
            *reinterpret_cast<u16x8*>(&lds_hi[nl * 136 + l * 8]) = o;
        }
    }

    // ================= MFMA phase (A-frags from LDS) =================
    const unsigned short* wfl1 = Wf1 + lane * 8;
    const unsigned short* wfl2 = Wf2 + lane * 8;
    const unsigned short* zlds = &lds_hi[m_ * 136 + q * 8];

    bf16x8 afrag[KC1];
#pragma unroll
    for (int c = 0; c < KC1; c++)
        afrag[c] = *reinterpret_cast<const bf16x8*>(zlds + c * 32);

    float b1v[8], b2v[8];
#pragma unroll
    for (int t = 0; t < 8; t++) {
        int col = t * 16 + m_;
        b1v[t] = flag ? ((const float*)bias1)[col]
                      : b2f(((const unsigned short*)bias1)[col]);
        b2v[t] = flag ? ((const float*)bias2)[col]
                      : b2f(((const unsigned short*)bias2)[col]);
    }

    f32x4 acc[8];
#pragma unroll
    for (int t = 0; t < 8; t++) acc[t] = (f32x4)(0.0f);

    // phase 1: mid = Z @ W1, weights double-buffered 8 fragments wide
    {
        bf16x8 wb[8], wn[8];
#pragma unroll
        for (int t = 0; t < 8; t++)
            wb[t] = *reinterpret_cast<const bf16x8*>(wfl1 + ((t * KC1 + 0) << 9));
#pragma unroll
        for (int c = 0; c < KC1; c++) {
            if (c + 1 < KC1) {
#pragma unroll
                for (int t = 0; t < 8; t++)
                    wn[t] = *reinterpret_cast<const bf16x8*>(wfl1 + ((t * KC1 + c + 1) << 9));
            }
#pragma unroll
            for (int t = 0; t < 8; t++)
                acc[t] = __builtin_amdgcn_mfma_f32_16x16x32_bf16(afrag[c], wb[t], acc[t], 0, 0, 0);
            if (c + 1 < KC1) {
#pragma unroll
                for (int t = 0; t < 8; t++) wb[t] = wn[t];
            }
        }
    }

    // epilogue 1: +b1, relu, hi/lo split -> LDS
#pragma unroll
    for (int r = 0; r < 4; r++) {
        int lr = q * 4 + r;
#pragma unroll
        for (int t = 0; t < 8; t++) {
            int col = t * 16 + m_;
            float v = acc[t][r] + b1v[t];
            v = v > 0.0f ? v : 0.0f;
            unsigned short hb = f2b(v);
            lds_hi[lr * 136 + col] = hb;
            lds_lo[lr * 136 + col] = f2b(v - b2f(hb));
        }
    }

#pragma unroll
    for (int t = 0; t < 8; t++) acc[t] = (f32x4)(0.0f);

    // phase 2: h = mid @ W2 (hi/lo from LDS), weights double-buffered
    {
        const unsigned short* hibase = &lds_hi[m_ * 136 + q * 8];
        const unsigned short* lobase = &lds_lo[m_ * 136 + q * 8];
        bf16x8 wb[8], wn[8];
#pragma unroll
        for (int t = 0; t < 8; t++)
            wb[t] = *reinterpret_cast<const bf16x8*>(wfl2 + ((t * 4 + 0) << 9));
#pragma unroll
        for (int c = 0; c < 4; c++) {
            if (c < 3) {
#pragma unroll
                for (int t = 0; t < 8; t++)
                    wn[t] = *reinterpret_cast<const bf16x8*>(wfl2 + ((t * 4 + c + 1) << 9));
            }
            bf16x8 ahi = *reinterpret_cast<const bf16x8*>(hibase + c * 32);
            bf16x8 alo = *reinterpret_cast<const bf16x8*>(lobase + c * 32);
#pragma unroll
            for (int t = 0; t < 8; t++) {
                acc[t] = __builtin_amdgcn_mfma_f32_16x16x32_bf16(ahi, wb[t], acc[t], 0, 0, 0);
                acc[t] = __builtin_amdgcn_mfma_f32_16x16x32_bf16(alo, wb[t], acc[t], 0, 0, 0);
            }
            if (c < 3) {
#pragma unroll
                for (int t = 0; t < 8; t++) wb[t] = wn[t];
            }
        }
    }

    // epilogue 2
#pragma unroll
    for (int r = 0; r < 4; r++) {
        int lr = q * 4 + r;
        int orow = blockIdx.x * 16 + lr;
#pragma unroll
        for (int t = 0; t < 8; t++) {
            int col = t * 16 + m_;
            float v = acc[t][r] + b2v[t];
            v = v > 0.0f ? v : 0.0f;
            if constexpr (POOL) {
                lds_hi[lr * 136 + col] = f2b(v);   // own wave's phase-2 reads done
            } else {
                Out[(size_t)orow * HID + col] = f2b(v);
            }
        }
    }

    if constexpr (POOL) {
        __syncthreads();   // single-wave: compiles to a waitcnt, orders LDS
        for (int f = lane; f < HID; f += 64) {
            int cur = -1;
            float sum = 0.0f, mx = 0.0f;
            for (int rrow = 0; rrow < 16; rrow++) {
                int g = batch_lds[rrow];
                float v = b2f(lds_hi[rrow * 136 + f]);
                if (g == cur) {
                    sum += v;
                    mx = fmaxf(mx, v);
                } else {
                    if (cur >= 0) {
                        atomicAdd(&psum[cur * HID + f], sum);
                        atomicMax(&pmax[cur * HID + f], __float_as_uint(mx));
                    }
                    cur = g; sum = v; mx = v;
                }
            }
            if (cur >= 0) {
                atomicAdd(&psum[cur * HID + f], sum);
                atomicMax(&pmax[cur * HID + f], __float_as_uint(mx));
            }
        }
    }
}

// ---------------- head: w1t[n][k] bf16 rows -> vectorized, unrolled dot ----------------
__global__ __launch_bounds__(128) void head_kernel(
    const float* __restrict__ psum, const unsigned int* __restrict__ pmax,
    const int* __restrict__ gstart,
    const unsigned short* __restrict__ w1t,
    const void* __restrict__ b1, const void* __restrict__ w2,
    const void* __restrict__ b2,
    void* __restrict__ out, const int* __restrict__ flagp) {
    int g = blockIdx.x;
    int n = threadIdx.x;
    int flag = *flagp;
    __shared__ float repr[2 * HID];
    __shared__ float red[HID];

    float c = (float)(gstart[g + 1] - gstart[g]);
    float inv = 1.0f / fmaxf(c, 1.0f);
    repr[n]       = psum[g * HID + n] * inv;
    repr[HID + n] = __uint_as_float(pmax[g * HID + n]);
    __syncthreads();

    const u16x8* wp = (const u16x8*)(w1t + n * 256);
    float a0 = 0.f, a1 = 0.f, a2 = 0.f, a3 = 0.f;
#pragma unroll
    for (int c8 = 0; c8 < 32; c8 += 4) {
        u16x8 w0 = wp[c8 + 0];
        u16x8 w1 = wp[c8 + 1];
        u16x8 w2v = wp[c8 + 2];
        u16x8 w3 = wp[c8 + 3];
#pragma unroll
        for (int j = 0; j < 8; j++) {
            a0 += repr[(c8 + 0) * 8 + j] * b2f(w0[j]);
            a1 += repr[(c8 + 1) * 8 + j] * b2f(w1[j]);
            a2 += repr[(c8 + 2) * 8 + j] * b2f(w2v[j]);
            a3 += repr[(c8 + 3) * 8 + j] * b2f(w3[j]);
        }
    }
    float b1v = flag ? ((const float*)b1)[n] : b2f(((const unsigned short*)b1)[n]);
    float acc = a0 + a1 + a2 + a3 + b1v;
    acc = fmaxf(acc, 0.0f);

    float w2s = flag ? ((const float*)w2)[n] : b2f(((const unsigned short*)w2)[n]);
    red[n] = acc * w2s;
    __syncthreads();
    for (int s = 64; s > 0; s >>= 1) {
        if (n < s) red[n] += red[n + s];
        __syncthreads();
    }
    if (n == 0) {
        float b2v = flag ? ((const float*)b2)[0] : b2f(((const unsigned short*)b2)[0]);
        float logit = red[0] + b2v;
        float sv = 1.0f / (1.0f + expf(-logit));
        if (flag) ((float*)out)[g] = sv;
        else      ((unsigned short*)out)[g] = f2b(sv);
    }
}

extern "C" void kernel_launch(void* const* d_in, const int* in_sizes, int n_in,
                              void* d_out, int out_size, void* d_ws, size_t ws_size,
                              hipStream_t stream) {
    const int* edge = (const int*)d_in[1];
    const int* srcv = edge;
    const int* dstv = edge + N_EDGES;
    const int* batch = (const int*)d_in[2];

    char* ws = (char*)d_ws;
    unsigned short* A = (unsigned short*)ws;               // 12.8 MB bf16 h (even)
    unsigned short* B = (unsigned short*)(ws + 12800000);  // 12.8 MB bf16 h (odd)
    unsigned int* ebuf = (unsigned int*)(ws + 25600000);   // 6.43 MB bucketed edges
    unsigned short* csr = (unsigned short*)(ws + 32100000);// 1.6 MB
    int* off    = (int*)(ws + 33700000);                   // 50001 ints
    unsigned short* wfbase = (unsigned short*)(ws + 33904000);  // 6 x 32 KB
    float* psum  = (float*)(ws + 34100608);                // 128 KB
    unsigned int* pmax = (unsigned int*)(ws + 34231680);   // 128 KB
    int* bcursor = (int*)(ws + 34362752);                  // 1 KB
    int* gstart  = (int*)(ws + 34363776);                  // 2 KB
    int* flagp   = (int*)(ws + 34365824);
    unsigned short* w1t = (unsigned short*)(ws + 34366848); // 64 KB

    const size_t NEED = 34500000;
    if (ws_size < NEED) {
        unsigned int k = 0;
        while ((((size_t)1) << (k + 1)) <= ws_size && k < 62) k++;
        diag_kernel<<<1, 256, 0, stream>>>((unsigned short*)d_out,
                                           (unsigned short)(0x4000 | (k & 63)));
        return;
    }

    mega_pre_kernel<<<581, 256, 0, stream>>>(
        (const unsigned short*)d_in[0],
        d_in[3], d_in[5], d_in[7], d_in[9], d_in[11], d_in[13], wfbase,
        batch, gstart, psum, pmax, d_in[15], w1t, bcursor, flagp);

    // CSR build: scatter into fixed buckets, then per-bucket sort
    const int EB = (N_EDGES + 4095) / 4096;   // 196
    bscatter_kernel<<<EB, 1024, 0, stream>>>(srcv, dstv, bcursor, ebuf);
    bsort_kernel<<<NBUCK, 256, 0, stream>>>(ebuf, bcursor, off, csr);

    const int GIN_GRID = N_NODES / 16;        // 3125 (exact)

    // layer 0: x -> A (fused gather_x + MLP0)
    fused_gin_kernel<64, false, true><<<GIN_GRID, 64, 0, stream>>>(
        d_in[0], off, csr,
        wfbase + 0 * 16384, d_in[4], wfbase + 1 * 16384, d_in[6],
        A, N_NODES, flagp, batch, psum, pmax);

    // layer 1: A -> B (fused gather128 + MLP1)
    fused_gin_kernel<128, false, false><<<GIN_GRID, 64, 0, stream>>>(
        A, off, csr,
        wfbase + 2 * 16384, d_in[8], wfbase + 3 * 16384, d_in[10],
        B, N_NODES, flagp, batch, psum, pmax);

    // layer 2: B -> pooled directly (fused gather128 + MLP2 + pool)
    fused_gin_kernel<128, true, false><<<GIN_GRID, 64, 0, stream>>>(
        B, off, csr,
        wfbase + 4 * 16384, d_in[12], wfbase + 5 * 16384, d_in[14],
        A /*unused*/, N_NODES, flagp, batch, psum, pmax);

    // head
    head_kernel<<<NUM_GRAPHS, 128, 0, stream>>>(psum, pmax, gstart, w1t,
                                                d_in[16], d_in[17], d_in[18],
                                                d_out, flagp);
}

// Round 7
// 249.223 us; speedup vs baseline: 1.2461x; 1.0489x over previous
//
#include <hip/hip_runtime.h>
#include <hip/hip_bf16.h>

#define N_NODES   50000
#define N_EDGES   800000
#define IN_DIM    64
#define HID       128
#define NUM_GRAPHS 256
#define NBUCK     196     // ceil(50000/256) buckets of 256 nodes
#define BCAP      8192    // fixed ebuf capacity per bucket (avg fill 4082)

typedef __bf16 bf16x8 __attribute__((ext_vector_type(8)));
typedef unsigned short u16x8 __attribute__((ext_vector_type(8)));
typedef float f32x4 __attribute__((ext_vector_type(4)));

__device__ __forceinline__ float b2f(unsigned short u) {
    return __uint_as_float(((unsigned int)u) << 16);
}
__device__ __forceinline__ unsigned short f2b(float f) {
    unsigned int x = __float_as_uint(f);
    x = (x + 0x7fffu + ((x >> 16) & 1u)) >> 16;   // RNE
    return (unsigned short)x;
}

__global__ void diag_kernel(unsigned short* out, unsigned short pat) {
    out[threadIdx.x] = pat;
}

// ---------------- mega preprocess ----------------
// blocks 0..351: GIN weight reorder; 352..547: graph ranges + pool zero;
// 548..579: head_w1 transpose -> w1t[n][k] bf16; 580: dtype probe + bucket cursor init
__global__ __launch_bounds__(256) void mega_pre_kernel(
    const unsigned short* __restrict__ x,
    const void* w0, const void* w1, const void* w2,
    const void* w3, const void* w4, const void* w5,
    unsigned short* __restrict__ wfbase,
    const int* __restrict__ batch, int* __restrict__ gstart,
    float* __restrict__ psum, unsigned int* __restrict__ pmax,
    const void* hw1, unsigned short* __restrict__ w1t,
    int* __restrict__ bcursor, int* __restrict__ flagp) {
    int b = blockIdx.x;
    int tid = threadIdx.x;

    if (b < 352) {
        __shared__ int cnt;
        if (tid == 0) cnt = 0;
        __syncthreads();
        unsigned short u = x[2 * tid];
        int e = (u >> 7) & 0xff;
        if (e <= 100 || e >= 140) atomicAdd(&cnt, 1);
        __syncthreads();
        int flag = cnt > 64;   // 1 = fp32, 0 = bf16

        int mat, boff;
        if (b < 32) { mat = 0; boff = b; }
        else { mat = 1 + (b - 32) / 64; boff = (b - 32) % 64; }
        const void* W = mat == 0 ? w0 : mat == 1 ? w1 : mat == 2 ? w2
                      : mat == 3 ? w3 : mat == 4 ? w4 : w5;
        int KC = (mat == 0) ? 2 : 4;
        int idx = boff * 256 + tid;
        int j  = idx & 7;
        int l  = (idx >> 3) & 63;
        int tc = idx >> 9;
        int c  = tc % KC;
        int t  = tc / KC;
        int k  = c * 32 + (l >> 4) * 8 + j;
        int n  = t * 16 + (l & 15);
        unsigned short v = flag ? f2b(((const float*)W)[k * 128 + n])
                                : ((const unsigned short*)W)[k * 128 + n];
        wfbase[mat * 16384 + idx] = v;
    } else if (b < 548) {
        int i = (b - 352) * 256 + tid;
        if (i < NUM_GRAPHS * HID) { psum[i] = 0.0f; pmax[i] = 0u; }
        if (i >= N_NODES) return;
        int b1 = batch[i];
        int b0 = (i == 0) ? -1 : batch[i - 1];
        for (int g = b0 + 1; g <= b1; g++) gstart[g] = i;
        if (i == N_NODES - 1)
            for (int g = b1 + 1; g <= NUM_GRAPHS; g++) gstart[g] = N_NODES;
    } else if (b < 580) {
        // head_w1 transpose: w1t[n*256 + k] = hw1[k*128 + n], bf16
        __shared__ int cnt;
        if (tid == 0) cnt = 0;
        __syncthreads();
        unsigned short u = x[2 * tid];
        int e = (u >> 7) & 0xff;
        if (e <= 100 || e >= 140) atomicAdd(&cnt, 1);
        __syncthreads();
        int flag = cnt > 64;
        int base = (b - 548) * 1024;
#pragma unroll
        for (int j = 0; j < 4; j++) {
            int idx = base + j * 256 + tid;   // [0, 32768)
            int n = idx >> 8;
            int k = idx & 255;
            unsigned short v = flag ? f2b(((const float*)hw1)[k * 128 + n])
                                    : ((const unsigned short*)hw1)[k * 128 + n];
            w1t[idx] = v;
        }
    } else {
        if (tid < NBUCK) bcursor[tid] = tid * BCAP;
        __shared__ int cnt;
        if (tid == 0) cnt = 0;
        __syncthreads();
        int c = 0;
        for (int j = 0; j < 16; j++) {
            unsigned short u = x[2 * (tid * 16 + j)];
            int e = (u >> 7) & 0xff;
            if (e <= 100 || e >= 140) c++;
        }
        atomicAdd(&cnt, c);
        __syncthreads();
        if (tid == 0) *flagp = (cnt > 1024) ? 1 : 0;
    }
}

// ---------------- CSR build: scatter into fixed-capacity bucket regions ----------------
__global__ __launch_bounds__(1024) void bscatter_kernel(const int* __restrict__ src,
        const int* __restrict__ dst, int* __restrict__ bcursor,
        unsigned int* __restrict__ ebuf) {
    __shared__ int lcnt[NBUCK];
    __shared__ int lbase[NBUCK];
    __shared__ int lcur[NBUCK];
    int tid = threadIdx.x;
    if (tid < NBUCK) lcnt[tid] = 0;
    __syncthreads();
    int e0 = blockIdx.x * 4096;
    int d[4], s[4];
#pragma unroll
    for (int k = 0; k < 4; k++) {
        int e = e0 + k * 1024 + tid;
        if (e < N_EDGES) {
            d[k] = dst[e]; s[k] = src[e];
            atomicAdd(&lcnt[d[k] >> 8], 1);
        } else d[k] = -1;
    }
    __syncthreads();
    if (tid < NBUCK) {
        int c = lcnt[tid];
        lbase[tid] = c ? atomicAdd(&bcursor[tid], c) : 0;
        lcur[tid] = 0;
    }
    __syncthreads();
#pragma unroll
    for (int k = 0; k < 4; k++) {
        if (d[k] >= 0) {
            int b = d[k] >> 8;
            int p = lbase[b] + atomicAdd(&lcur[b], 1);
            ebuf[p] = ((unsigned int)(d[k] & 255) << 16) | (unsigned int)s[k];
        }
    }
}

// per-bucket counting sort -> compact off + csr; bucket counts/bases derived
// from final cursors via a redundant in-block 196-scan (replaces bscan pass).
__global__ __launch_bounds__(256) void bsort_kernel(const unsigned int* __restrict__ ebuf,
        const int* __restrict__ bcursor, int* __restrict__ off,
        unsigned short* __restrict__ csr) {
    __shared__ int cntA[256];
    __shared__ int sc[256];
    __shared__ int lcnt[256];
    __shared__ int lcur[256];
    int b = blockIdx.x, tid = threadIdx.x;

    int v = (tid < NBUCK) ? (bcursor[tid] - tid * BCAP) : 0;
    cntA[tid] = v;
    sc[tid] = v;
    __syncthreads();
    for (int d = 1; d < 256; d <<= 1) {
        int t = (tid >= d) ? sc[tid - d] : 0;
        __syncthreads();
        sc[tid] += t;
        __syncthreads();
    }
    int base = sc[b] - cntA[b];   // exclusive prefix for this bucket
    int cnt  = cntA[b];
    int ebase = b * BCAP;
    __syncthreads();

    lcnt[tid] = 0;
    __syncthreads();
    for (int i = tid; i < cnt; i += 256)
        atomicAdd(&lcnt[ebuf[ebase + i] >> 16], 1);
    __syncthreads();
    int v2 = lcnt[tid];
    sc[tid] = v2;
    __syncthreads();
    for (int d = 1; d < 256; d <<= 1) {
        int t = (tid >= d) ? sc[tid - d] : 0;
        __syncthreads();
        sc[tid] += t;
        __syncthreads();
    }
    int excl = sc[tid] - v2;
    lcur[tid] = excl;
    int node = b * 256 + tid;
    if (node < N_NODES) off[node] = base + excl;
    if (b == 0 && tid == 0) off[N_NODES] = N_EDGES;
    __syncthreads();
    for (int i = tid; i < cnt; i += 256) {
        unsigned int ev = ebuf[ebase + i];
        int p = atomicAdd(&lcur[ev >> 16], 1);
        csr[base + p] = (unsigned short)(ev & 0xffffu);
    }
}

// ---------------- fused gather + GIN MLP (R3 structure + 8-deep gather ILP) ----------------
// One block = 64 output rows, 4 waves. Each wave gathers its own 16 rows
// (4 nodes/pass, 16 lanes each) into wave-private rows of lds_hi (z tile),
// then runs the MFMA body reading A-fragments from LDS. No barrier needed:
// rows are wave-private; fast waves slide past slow ones (degree variance).
// R6->R7 change: gather main loop 8-deep (8 outstanding row loads/lane) to
// halve latency-exposed waits. POOL=true: in-block pooling (layer 2).
template <int K1, bool POOL, bool FROMX>
__global__ __launch_bounds__(256, 3) void fused_gin_kernel(
    const void* __restrict__ X,
    const int* __restrict__ off, const unsigned short* __restrict__ csr,
    const unsigned short* __restrict__ Wf1, const void* __restrict__ bias1,
    const unsigned short* __restrict__ Wf2, const void* __restrict__ bias2,
    unsigned short* __restrict__ Out, int M, const int* __restrict__ flagp,
    const int* __restrict__ batch, float* __restrict__ psum,
    unsigned int* __restrict__ pmax) {
    constexpr int KC1 = K1 / 32;
    __shared__ __align__(16) unsigned short lds_hi[64 * 136];
    __shared__ __align__(16) unsigned short lds_lo[64 * 136];
    __shared__ int batch_lds[64];

    int flag = *flagp;
    int wave = threadIdx.x >> 6;
    int lane = threadIdx.x & 63;
    int m_ = lane & 15;
    int q  = lane >> 4;

    if constexpr (POOL) {
        if (threadIdx.x < 64) {
            int gr = blockIdx.x * 64 + threadIdx.x;
            batch_lds[threadIdx.x] = gr < M ? batch[gr] : -1;
        }
    }

    // ================= gather phase (wave-private rows) =================
    int np = lane >> 4;      // node within pass (0..3)
    int l  = lane & 15;      // feat-lane within node
#pragma unroll 1
    for (int p = 0; p < 4; p++) {
        int nl = wave * 16 + p * 4 + np;           // node_local 0..63
        int node = blockIdx.x * 64 + nl;
        int nodec = node < M ? node : (M - 1);
        int s = off[nodec], e = off[nodec + 1];
        if constexpr (FROMX) {
            float a0, a1, a2, a3;
            float b0 = 0.f, b1 = 0.f, b2 = 0.f, b3 = 0.f;
            float c0 = 0.f, c1 = 0.f, c2 = 0.f, c3 = 0.f;
            float d0 = 0.f, d1 = 0.f, d2 = 0.f, d3 = 0.f;
            if (flag) {
                const float4* xp = (const float4*)X;
                float4 u = xp[(size_t)nodec * 16 + l];
                a0 = u.x; a1 = u.y; a2 = u.z; a3 = u.w;
                int i = s;
                for (; i + 7 < e; i += 8) {
                    float4 v0 = xp[(size_t)csr[i] * 16 + l];
                    float4 v1 = xp[(size_t)csr[i + 1] * 16 + l];
                    float4 v2 = xp[(size_t)csr[i + 2] * 16 + l];
                    float4 v3 = xp[(size_t)csr[i + 3] * 16 + l];
                    float4 v4 = xp[(size_t)csr[i + 4] * 16 + l];
                    float4 v5 = xp[(size_t)csr[i + 5] * 16 + l];
                    float4 v6 = xp[(size_t)csr[i + 6] * 16 + l];
                    float4 v7 = xp[(size_t)csr[i + 7] * 16 + l];
                    a0 += v0.x; a1 += v0.y; a2 += v0.z; a3 += v0.w;
                    b0 += v1.x; b1 += v1.y; b2 += v1.z; b3 += v1.w;
                    c0 += v2.x; c1 += v2.y; c2 += v2.z; c3 += v2.w;
                    d0 += v3.x; d1 += v3.y; d2 += v3.z; d3 += v3.w;
                    a0 += v4.x; a1 += v4.y; a2 += v4.z; a3 += v4.w;
                    b0 += v5.x; b1 += v5.y; b2 += v5.z; b3 += v5.w;
                    c0 += v6.x; c1 += v6.y; c2 += v6.z; c3 += v6.w;
                    d0 += v7.x; d1 += v7.y; d2 += v7.z; d3 += v7.w;
                }
                for (; i + 3 < e; i += 4) {
                    float4 v0 = xp[(size_t)csr[i] * 16 + l];
                    float4 v1 = xp[(size_t)csr[i + 1] * 16 + l];
                    float4 v2 = xp[(size_t)csr[i + 2] * 16 + l];
                    float4 v3 = xp[(size_t)csr[i + 3] * 16 + l];
                    a0 += v0.x; a1 += v0.y; a2 += v0.z; a3 += v0.w;
                    b0 += v1.x; b1 += v1.y; b2 += v1.z; b3 += v1.w;
                    c0 += v2.x; c1 += v2.y; c2 += v2.z; c3 += v2.w;
                    d0 += v3.x; d1 += v3.y; d2 += v3.z; d3 += v3.w;
                }
                for (; i < e; i++) {
                    float4 v = xp[(size_t)csr[i] * 16 + l];
                    a0 += v.x; a1 += v.y; a2 += v.z; a3 += v.w;
                }
            } else {
                const ushort4* xp = (const ushort4*)X;
                ushort4 u = xp[(size_t)nodec * 16 + l];
                a0 = b2f(u.x); a1 = b2f(u.y); a2 = b2f(u.z); a3 = b2f(u.w);
                int i = s;
                for (; i + 7 < e; i += 8) {
                    ushort4 v0 = xp[(size_t)csr[i] * 16 + l];
                    ushort4 v1 = xp[(size_t)csr[i + 1] * 16 + l];
                    ushort4 v2 = xp[(size_t)csr[i + 2] * 16 + l];
                    ushort4 v3 = xp[(size_t)csr[i + 3] * 16 + l];
                    ushort4 v4 = xp[(size_t)csr[i + 4] * 16 + l];
                    ushort4 v5 = xp[(size_t)csr[i + 5] * 16 + l];
                    ushort4 v6 = xp[(size_t)csr[i + 6] * 16 + l];
                    ushort4 v7 = xp[(size_t)csr[i + 7] * 16 + l];
                    a0 += b2f(v0.x); a1 += b2f(v0.y); a2 += b2f(v0.z); a3 += b2f(v0.w);
                    b0 += b2f(v1.x); b1 += b2f(v1.y); b2 += b2f(v1.z); b3 += b2f(v1.w);
                    c0 += b2f(v2.x); c1 += b2f(v2.y); c2 += b2f(v2.z); c3 += b2f(v2.w);
                    d0 += b2f(v3.x); d1 += b2f(v3.y); d2 += b2f(v3.z); d3 += b2f(v3.w);
                    a0 += b2f(v4.x); a1 += b2f(v4.y); a2 += b2f(v4.z); a3 += b2f(v4.w);
                    b0 += b2f(v5.x); b1 += b2f(v5.y); b2 += b2f(v5.z); b3 += b2f(v5.w);
                    c0 += b2f(v6.x); c1 += b2f(v6.y); c2 += b2f(v6.z); c3 += b2f(v6.w);
                    d0 += b2f(v7.x); d1 += b2f(v7.y); d2 += b2f(v7.z); d3 += b2f(v7.w);
                }
                for (; i + 3 < e; i += 4) {
                    ushort4 v0 = xp[(size_t)csr[i] * 16 + l];
                    ushort4 v1 = xp[(size_t)csr[i + 1] * 16 + l];
                    ushort4 v2 = xp[(size_t)csr[i + 2] * 16 + l];
                    ushort4 v3 = xp[(size_t)csr[i + 3] * 16 + l];
                    a0 += b2f(v0.x); a1 += b2f(v0.y); a2 += b2f(v0.z); a3 += b2f(v0.w);
                    b0 += b2f(v1.x); b1 += b2f(v1.y); b2 += b2f(v1.z); b3 += b2f(v1.w);
                    c0 += b2f(v2.x); c1 += b2f(v2.y); c2 += b2f(v2.z); c3 += b2f(v2.w);
                    d0 += b2f(v3.x); d1 += b2f(v3.y); d2 += b2f(v3.z); d3 += b2f(v3.w);
                }
                for (; i < e; i++) {
                    ushort4 v = xp[(size_t)csr[i] * 16 + l];
                    a0 += b2f(v.x); a1 += b2f(v.y); a2 += b2f(v.z); a3 += b2f(v.w);
                }
            }
            ushort4 o;
            o.x = f2b(a0 + b0 + c0 + d0);
            o.y = f2b(a1 + b1 + c1 + d1);
            o.z = f2b(a2 + b2 + c2 + d2);
            o.w = f2b(a3 + b3 + c3 + d3);
            *reinterpret_cast<ushort4*>(&lds_hi[nl * 136 + l * 4]) = o;
        } else {
            const u16x8* hp = (const u16x8*)X;
            u16x8 u = hp[(size_t)nodec * 16 + l];
            float a[8], b[8], c[8], d[8];
#pragma unroll
            for (int j = 0; j < 8; j++) { a[j] = b2f(u[j]); b[j] = 0.f; c[j] = 0.f; d[j] = 0.f; }
            int i = s;
            for (; i + 7 < e; i += 8) {
                u16x8 v0 = hp[(size_t)csr[i] * 16 + l];
                u16x8 v1 = hp[(size_t)csr[i + 1] * 16 + l];
                u16x8 v2 = hp[(size_t)csr[i + 2] * 16 + l];
                u16x8 v3 = hp[(size_t)csr[i + 3] * 16 + l];
                u16x8 v4 = hp[(size_t)csr[i + 4] * 16 + l];
                u16x8 v5 = hp[(size_t)csr[i + 5] * 16 + l];
                u16x8 v6 = hp[(size_t)csr[i + 6] * 16 + l];
                u16x8 v7 = hp[(size_t)csr[i + 7] * 16 + l];
#pragma unroll
                for (int j = 0; j < 8; j++) {
                    a[j] += b2f(v0[j]); b[j] += b2f(v1[j]);
                    c[j] += b2f(v2[j]); d[j] += b2f(v3[j]);
                }
#pragma unroll
                for (int j = 0; j < 8; j++) {
                    a[j] += b2f(v4[j]); b[j] += b2f(v5[j]);
                    c[j] += b2f(v6[j]); d[j] += b2f(v7[j]);
                }
            }
            for (; i + 3 < e; i += 4) {
                u16x8 v0 = hp[(size_t)csr[i] * 16 + l];
                u16x8 v1 = hp[(size_t)csr[i + 1] * 16 + l];
                u16x8 v2 = hp[(size_t)csr[i + 2] * 16 + l];
                u16x8 v3 = hp[(size_t)csr[i + 3] * 16 + l];
#pragma unroll
                for (int j = 0; j < 8; j++) {
                    a[j] += b2f(v0[j]); b[j] += b2f(v1[j]);
                    c[j] += b2f(v2[j]); d[j] += b2f(v3[j]);
                }
            }
            for (; i < e; i++) {
                u16x8 v = hp[(size_t)csr[i] * 16 + l];
#pragma unroll
                for (int j = 0; j < 8; j++) a[j] += b2f(v[j]);
            }
            u16x8 o;
#pragma unroll
            for (int j = 0; j < 8; j++) o[j] = f2b(a[j] + b[j] + c[j] + d[j]);
            *reinterpret_cast<u16x8*>(&lds_hi[nl * 136 + l * 8]) = o;
        }
    }

    // ================= MFMA phase (A-frags from LDS) =================
    const unsigned short* wfl1 = Wf1 + lane * 8;
    const unsigned short* wfl2 = Wf2 + lane * 8;
    const unsigned short* zlds = &lds_hi[(wave * 16 + m_) * 136 + q * 8];

    bf16x8 afrag[KC1];
#pragma unroll
    for (int c = 0; c < KC1; c++)
        afrag[c] = *reinterpret_cast<const bf16x8*>(zlds + c * 32);

    float b1v[8], b2v[8];
#pragma unroll
    for (int t = 0; t < 8; t++) {
        int col = t * 16 + m_;
        b1v[t] = flag ? ((const float*)bias1)[col]
                      : b2f(((const unsigned short*)bias1)[col]);
        b2v[t] = flag ? ((const float*)bias2)[col]
                      : b2f(((const unsigned short*)bias2)[col]);
    }

    f32x4 acc[8];
#pragma unroll
    for (int t = 0; t < 8; t++) acc[t] = (f32x4)(0.0f);

    // phase 1: mid = Z @ W1, weights double-buffered 8 fragments wide
    {
        bf16x8 wb[8], wn[8];
#pragma unroll
        for (int t = 0; t < 8; t++)
            wb[t] = *reinterpret_cast<const bf16x8*>(wfl1 + ((t * KC1 + 0) << 9));
#pragma unroll
        for (int c = 0; c < KC1; c++) {
            if (c + 1 < KC1) {
#pragma unroll
                for (int t = 0; t < 8; t++)
                    wn[t] = *reinterpret_cast<const bf16x8*>(wfl1 + ((t * KC1 + c + 1) << 9));
            }
#pragma unroll
            for (int t = 0; t < 8; t++)
                acc[t] = __builtin_amdgcn_mfma_f32_16x16x32_bf16(afrag[c], wb[t], acc[t], 0, 0, 0);
            if (c + 1 < KC1) {
#pragma unroll
                for (int t = 0; t < 8; t++) wb[t] = wn[t];
            }
        }
    }

    // epilogue 1: +b1, relu, hi/lo split -> LDS
#pragma unroll
    for (int r = 0; r < 4; r++) {
        int lr = wave * 16 + q * 4 + r;
#pragma unroll
        for (int t = 0; t < 8; t++) {
            int col = t * 16 + m_;
            float v = acc[t][r] + b1v[t];
            v = v > 0.0f ? v : 0.0f;
            unsigned short hb = f2b(v);
            lds_hi[lr * 136 + col] = hb;
            lds_lo[lr * 136 + col] = f2b(v - b2f(hb));
        }
    }

#pragma unroll
    for (int t = 0; t < 8; t++) acc[t] = (f32x4)(0.0f);

    // phase 2: h = mid @ W2 (hi/lo from LDS), weights double-buffered
    {
        int lr2 = wave * 16 + m_;
        const unsigned short* hibase = &lds_hi[lr2 * 136 + q * 8];
        const unsigned short* lobase = &lds_lo[lr2 * 136 + q * 8];
        bf16x8 wb[8], wn[8];
#pragma unroll
        for (int t = 0; t < 8; t++)
            wb[t] = *reinterpret_cast<const bf16x8*>(wfl2 + ((t * 4 + 0) << 9));
#pragma unroll
        for (int c = 0; c < 4; c++) {
            if (c < 3) {
#pragma unroll
                for (int t = 0; t < 8; t++)
                    wn[t] = *reinterpret_cast<const bf16x8*>(wfl2 + ((t * 4 + c + 1) << 9));
            }
            bf16x8 ahi = *reinterpret_cast<const bf16x8*>(hibase + c * 32);
            bf16x8 alo = *reinterpret_cast<const bf16x8*>(lobase + c * 32);
#pragma unroll
            for (int t = 0; t < 8; t++) {
                acc[t] = __builtin_amdgcn_mfma_f32_16x16x32_bf16(ahi, wb[t], acc[t], 0, 0, 0);
                acc[t] = __builtin_amdgcn_mfma_f32_16x16x32_bf16(alo, wb[t], acc[t], 0, 0, 0);
            }
            if (c < 3) {
#pragma unroll
                for (int t = 0; t < 8; t++) wb[t] = wn[t];
            }
        }
    }

    // epilogue 2
#pragma unroll
    for (int r = 0; r < 4; r++) {
        int lr = wave * 16 + q * 4 + r;
        int orow = blockIdx.x * 64 + lr;
#pragma unroll
        for (int t = 0; t < 8; t++) {
            int col = t * 16 + m_;
            float v = acc[t][r] + b2v[t];
            v = v > 0.0f ? v : 0.0f;
            if constexpr (POOL) {
                lds_hi[lr * 136 + col] = f2b(v);   // safe: own rows' phase-2 reads done
            } else {
                if (orow < M) Out[(size_t)orow * HID + col] = f2b(v);
            }
        }
    }

    if constexpr (POOL) {
        __syncthreads();
        int f = threadIdx.x;
        if (f < HID) {
            int cur = -1;
            float sum = 0.0f, mx = 0.0f;
            for (int rrow = 0; rrow < 64; rrow++) {
                int g = batch_lds[rrow];
                if (g < 0) break;   // tail padding
                float v = b2f(lds_hi[rrow * 136 + f]);
                if (g == cur) {
                    sum += v;
                    mx = fmaxf(mx, v);
                } else {
                    if (cur >= 0) {
                        atomicAdd(&psum[cur * HID + f], sum);
                        atomicMax(&pmax[cur * HID + f], __float_as_uint(mx));
                    }
                    cur = g; sum = v; mx = v;
                }
            }
            if (cur >= 0) {
                atomicAdd(&psum[cur * HID + f], sum);
                atomicMax(&pmax[cur * HID + f], __float_as_uint(mx));
            }
        }
    }
}

// ---------------- head: w1t[n][k] bf16 rows -> vectorized, unrolled dot ----------------
__global__ __launch_bounds__(128) void head_kernel(
    const float* __restrict__ psum, const unsigned int* __restrict__ pmax,
    const int* __restrict__ gstart,
    const unsigned short* __restrict__ w1t,
    const void* __restrict__ b1, const void* __restrict__ w2,
    const void* __restrict__ b2,
    void* __restrict__ out, const int* __restrict__ flagp) {
    int g = blockIdx.x;
    int n = threadIdx.x;
    int flag = *flagp;
    __shared__ float repr[2 * HID];
    __shared__ float red[HID];

    float c = (float)(gstart[g + 1] - gstart[g]);
    float inv = 1.0f / fmaxf(c, 1.0f);
    repr[n]       = psum[g * HID + n] * inv;
    repr[HID + n] = __uint_as_float(pmax[g * HID + n]);
    __syncthreads();

    const u16x8* wp = (const u16x8*)(w1t + n * 256);
    float a0 = 0.f, a1 = 0.f, a2 = 0.f, a3 = 0.f;
#pragma unroll
    for (int c8 = 0; c8 < 32; c8 += 4) {
        u16x8 w0 = wp[c8 + 0];
        u16x8 w1 = wp[c8 + 1];
        u16x8 w2v = wp[c8 + 2];
        u16x8 w3 = wp[c8 + 3];
#pragma unroll
        for (int j = 0; j < 8; j++) {
            a0 += repr[(c8 + 0) * 8 + j] * b2f(w0[j]);
            a1 += repr[(c8 + 1) * 8 + j] * b2f(w1[j]);
            a2 += repr[(c8 + 2) * 8 + j] * b2f(w2v[j]);
            a3 += repr[(c8 + 3) * 8 + j] * b2f(w3[j]);
        }
    }
    float b1v = flag ? ((const float*)b1)[n] : b2f(((const unsigned short*)b1)[n]);
    float acc = a0 + a1 + a2 + a3 + b1v;
    acc = fmaxf(acc, 0.0f);

    float w2s = flag ? ((const float*)w2)[n] : b2f(((const unsigned short*)w2)[n]);
    red[n] = acc * w2s;
    __syncthreads();
    for (int s = 64; s > 0; s >>= 1) {
        if (n < s) red[n] += red[n + s];
        __syncthreads();
    }
    if (n == 0) {
        float b2v = flag ? ((const float*)b2)[0] : b2f(((const unsigned short*)b2)[0]);
        float logit = red[0] + b2v;
        float sv = 1.0f / (1.0f + expf(-logit));
        if (flag) ((float*)out)[g] = sv;
        else      ((unsigned short*)out)[g] = f2b(sv);
    }
}

extern "C" void kernel_launch(void* const* d_in, const int* in_sizes, int n_in,
                              void* d_out, int out_size, void* d_ws, size_t ws_size,
                              hipStream_t stream) {
    const int* edge = (const int*)d_in[1];
    const int* srcv = edge;
    const int* dstv = edge + N_EDGES;
    const int* batch = (const int*)d_in[2];

    char* ws = (char*)d_ws;
    unsigned short* A = (unsigned short*)ws;               // 12.8 MB bf16 h (even)
    unsigned short* B = (unsigned short*)(ws + 12800000);  // 12.8 MB bf16 h (odd)
    unsigned int* ebuf = (unsigned int*)(ws + 25600000);   // 6.43 MB bucketed edges
    unsigned short* csr = (unsigned short*)(ws + 32100000);// 1.6 MB
    int* off    = (int*)(ws + 33700000);                   // 50001 ints
    unsigned short* wfbase = (unsigned short*)(ws + 33904000);  // 6 x 32 KB
    float* psum  = (float*)(ws + 34100608);                // 128 KB
    unsigned int* pmax = (unsigned int*)(ws + 34231680);   // 128 KB
    int* bcursor = (int*)(ws + 34362752);                  // 1 KB
    int* gstart  = (int*)(ws + 34363776);                  // 2 KB
    int* flagp   = (int*)(ws + 34365824);
    unsigned short* w1t = (unsigned short*)(ws + 34366848); // 64 KB

    const size_t NEED = 34500000;
    if (ws_size < NEED) {
        unsigned int k = 0;
        while ((((size_t)1) << (k + 1)) <= ws_size && k < 62) k++;
        diag_kernel<<<1, 256, 0, stream>>>((unsigned short*)d_out,
                                           (unsigned short)(0x4000 | (k & 63)));
        return;
    }

    mega_pre_kernel<<<581, 256, 0, stream>>>(
        (const unsigned short*)d_in[0],
        d_in[3], d_in[5], d_in[7], d_in[9], d_in[11], d_in[13], wfbase,
        batch, gstart, psum, pmax, d_in[15], w1t, bcursor, flagp);

    // CSR build: scatter into fixed buckets, then per-bucket sort
    const int EB = (N_EDGES + 4095) / 4096;   // 196
    bscatter_kernel<<<EB, 1024, 0, stream>>>(srcv, dstv, bcursor, ebuf);
    bsort_kernel<<<NBUCK, 256, 0, stream>>>(ebuf, bcursor, off, csr);

    const int GEMM_GRID = (N_NODES + 63) / 64;   // 782

    // layer 0: x -> A (fused gather_x + MLP0)
    fused_gin_kernel<64, false, true><<<GEMM_GRID, 256, 0, stream>>>(
        d_in[0], off, csr,
        wfbase + 0 * 16384, d_in[4], wfbase + 1 * 16384, d_in[6],
        A, N_NODES, flagp, batch, psum, pmax);

    // layer 1: A -> B (fused gather128 + MLP1)
    fused_gin_kernel<128, false, false><<<GEMM_GRID, 256, 0, stream>>>(
        A, off, csr,
        wfbase + 2 * 16384, d_in[8], wfbase + 3 * 16384, d_in[10],
        B, N_NODES, flagp, batch, psum, pmax);

    // layer 2: B -> pooled directly (fused gather128 + MLP2 + pool)
    fused_gin_kernel<128, true, false><<<GEMM_GRID, 256, 0, stream>>>(
        B, off, csr,
        wfbase + 4 * 16384, d_in[12], wfbase + 5 * 16384, d_in[14],
        A /*unused*/, N_NODES, flagp, batch, psum, pmax);

    // head
    head_kernel<<<NUM_GRAPHS, 128, 0, stream>>>(psum, pmax, gstart, w1t,
                                                d_in[16], d_in[17], d_in[18],
                                                d_out, flagp);
}

// Round 8
// 248.635 us; speedup vs baseline: 1.2491x; 1.0024x over previous
//
#include <hip/hip_runtime.h>
#include <hip/hip_bf16.h>

#define N_NODES   50000
#define N_EDGES   800000
#define IN_DIM    64
#define HID       128
#define NUM_GRAPHS 256
#define NBUCK     196     // ceil(50000/256) buckets of 256 nodes
#define BCAP      8192    // fixed ebuf capacity per bucket (avg fill 4082)
#define CPAD      16      // bcursor padding: 16 ints = 64 B per counter

typedef __bf16 bf16x8 __attribute__((ext_vector_type(8)));
typedef unsigned short u16x8 __attribute__((ext_vector_type(8)));
typedef float f32x4 __attribute__((ext_vector_type(4)));

__device__ __forceinline__ float b2f(unsigned short u) {
    return __uint_as_float(((unsigned int)u) << 16);
}
__device__ __forceinline__ unsigned short f2b(float f) {
    unsigned int x = __float_as_uint(f);
    x = (x + 0x7fffu + ((x >> 16) & 1u)) >> 16;   // RNE
    return (unsigned short)x;
}

__global__ void diag_kernel(unsigned short* out, unsigned short pat) {
    out[threadIdx.x] = pat;
}

// ---------------- mega preprocess ----------------
// blocks 0..351: GIN weight reorder; 352..547: graph ranges + pool zero;
// 548..579: head_w1 transpose -> w1t[n][k] bf16; 580: dtype probe + bucket cursor init
__global__ __launch_bounds__(256) void mega_pre_kernel(
    const unsigned short* __restrict__ x,
    const void* w0, const void* w1, const void* w2,
    const void* w3, const void* w4, const void* w5,
    unsigned short* __restrict__ wfbase,
    const int* __restrict__ batch, int* __restrict__ gstart,
    float* __restrict__ psum, unsigned int* __restrict__ pmax,
    const void* hw1, unsigned short* __restrict__ w1t,
    int* __restrict__ bcursor, int* __restrict__ flagp) {
    int b = blockIdx.x;
    int tid = threadIdx.x;

    if (b < 352) {
        __shared__ int cnt;
        if (tid == 0) cnt = 0;
        __syncthreads();
        unsigned short u = x[2 * tid];
        int e = (u >> 7) & 0xff;
        if (e <= 100 || e >= 140) atomicAdd(&cnt, 1);
        __syncthreads();
        int flag = cnt > 64;   // 1 = fp32, 0 = bf16

        int mat, boff;
        if (b < 32) { mat = 0; boff = b; }
        else { mat = 1 + (b - 32) / 64; boff = (b - 32) % 64; }
        const void* W = mat == 0 ? w0 : mat == 1 ? w1 : mat == 2 ? w2
                      : mat == 3 ? w3 : mat == 4 ? w4 : w5;
        int KC = (mat == 0) ? 2 : 4;
        int idx = boff * 256 + tid;
        int j  = idx & 7;
        int l  = (idx >> 3) & 63;
        int tc = idx >> 9;
        int c  = tc % KC;
        int t  = tc / KC;
        int k  = c * 32 + (l >> 4) * 8 + j;
        int n  = t * 16 + (l & 15);
        unsigned short v = flag ? f2b(((const float*)W)[k * 128 + n])
                                : ((const unsigned short*)W)[k * 128 + n];
        wfbase[mat * 16384 + idx] = v;
    } else if (b < 548) {
        int i = (b - 352) * 256 + tid;
        if (i < NUM_GRAPHS * HID) { psum[i] = 0.0f; pmax[i] = 0u; }
        if (i >= N_NODES) return;
        int b1 = batch[i];
        int b0 = (i == 0) ? -1 : batch[i - 1];
        for (int g = b0 + 1; g <= b1; g++) gstart[g] = i;
        if (i == N_NODES - 1)
            for (int g = b1 + 1; g <= NUM_GRAPHS; g++) gstart[g] = N_NODES;
    } else if (b < 580) {
        // head_w1 transpose: w1t[n*256 + k] = hw1[k*128 + n], bf16
        __shared__ int cnt;
        if (tid == 0) cnt = 0;
        __syncthreads();
        unsigned short u = x[2 * tid];
        int e = (u >> 7) & 0xff;
        if (e <= 100 || e >= 140) atomicAdd(&cnt, 1);
        __syncthreads();
        int flag = cnt > 64;
        int base = (b - 548) * 1024;
#pragma unroll
        for (int j = 0; j < 4; j++) {
            int idx = base + j * 256 + tid;   // [0, 32768)
            int n = idx >> 8;
            int k = idx & 255;
            unsigned short v = flag ? f2b(((const float*)hw1)[k * 128 + n])
                                    : ((const unsigned short*)hw1)[k * 128 + n];
            w1t[idx] = v;
        }
    } else {
        if (tid < NBUCK) bcursor[tid * CPAD] = tid * BCAP;   // padded: 1 counter / 64B line
        __shared__ int cnt;
        if (tid == 0) cnt = 0;
        __syncthreads();
        int c = 0;
        for (int j = 0; j < 16; j++) {
            unsigned short u = x[2 * (tid * 16 + j)];
            int e = (u >> 7) & 0xff;
            if (e <= 100 || e >= 140) c++;
        }
        atomicAdd(&cnt, c);
        __syncthreads();
        if (tid == 0) *flagp = (cnt > 1024) ? 1 : 0;
    }
}

// ---------------- CSR build: scatter into fixed-capacity bucket regions ----------------
__global__ __launch_bounds__(1024) void bscatter_kernel(const int* __restrict__ src,
        const int* __restrict__ dst, int* __restrict__ bcursor,
        unsigned int* __restrict__ ebuf) {
    __shared__ int lcnt[NBUCK];
    __shared__ int lbase[NBUCK];
    __shared__ int lcur[NBUCK];
    int tid = threadIdx.x;
    if (tid < NBUCK) lcnt[tid] = 0;
    __syncthreads();
    int e0 = blockIdx.x * 4096;
    int d[4], s[4];
#pragma unroll
    for (int k = 0; k < 4; k++) {
        int e = e0 + k * 1024 + tid;
        if (e < N_EDGES) {
            d[k] = dst[e]; s[k] = src[e];
            atomicAdd(&lcnt[d[k] >> 8], 1);
        } else d[k] = -1;
    }
    __syncthreads();
    if (tid < NBUCK) {
        int c = lcnt[tid];
        lbase[tid] = c ? atomicAdd(&bcursor[tid * CPAD], c) : 0;   // padded counters
        lcur[tid] = 0;
    }
    __syncthreads();
#pragma unroll
    for (int k = 0; k < 4; k++) {
        if (d[k] >= 0) {
            int b = d[k] >> 8;
            int p = lbase[b] + atomicAdd(&lcur[b], 1);
            ebuf[p] = ((unsigned int)(d[k] & 255) << 16) | (unsigned int)s[k];
        }
    }
}

// per-bucket counting sort -> compact off + csr; bucket counts/bases derived
// from final cursors via a redundant in-block 196-scan. R8: 512 threads to
// halve the serial latency-exposed iterations per pass (196 blocks < 1/CU).
__global__ __launch_bounds__(512) void bsort_kernel(const unsigned int* __restrict__ ebuf,
        const int* __restrict__ bcursor, int* __restrict__ off,
        unsigned short* __restrict__ csr) {
    __shared__ int cntA[256];
    __shared__ int sc[256];
    __shared__ int lcnt[256];
    __shared__ int lcur[256];
    int b = blockIdx.x, tid = threadIdx.x;

    if (tid < 256) {
        int v = (tid < NBUCK) ? (bcursor[tid * CPAD] - tid * BCAP) : 0;
        cntA[tid] = v;
        sc[tid] = v;
    }
    __syncthreads();
    for (int d = 1; d < 256; d <<= 1) {
        int t = (tid >= d && tid < 256) ? sc[tid - d] : 0;
        __syncthreads();
        if (tid < 256) sc[tid] += t;
        __syncthreads();
    }
    int base = sc[b] - cntA[b];   // exclusive prefix for this bucket
    int cnt  = cntA[b];
    int ebase = b * BCAP;
    __syncthreads();

    if (tid < 256) lcnt[tid] = 0;
    __syncthreads();
    for (int i = tid; i < cnt; i += 512)
        atomicAdd(&lcnt[ebuf[ebase + i] >> 16], 1);
    __syncthreads();
    int v2 = 0;
    if (tid < 256) {
        v2 = lcnt[tid];
        sc[tid] = v2;
    }
    __syncthreads();
    for (int d = 1; d < 256; d <<= 1) {
        int t = (tid >= d && tid < 256) ? sc[tid - d] : 0;
        __syncthreads();
        if (tid < 256) sc[tid] += t;
        __syncthreads();
    }
    if (tid < 256) {
        int excl = sc[tid] - v2;
        lcur[tid] = excl;
        int node = b * 256 + tid;
        if (node < N_NODES) off[node] = base + excl;
    }
    if (b == 0 && tid == 0) off[N_NODES] = N_EDGES;
    __syncthreads();
    for (int i = tid; i < cnt; i += 512) {
        unsigned int ev = ebuf[ebase + i];
        int p = atomicAdd(&lcur[ev >> 16], 1);
        csr[base + p] = (unsigned short)(ev & 0xffffu);
    }
}

// ---------------- fused gather + GIN MLP (R7 best-known, unchanged) ----------------
template <int K1, bool POOL, bool FROMX>
__global__ __launch_bounds__(256, 3) void fused_gin_kernel(
    const void* __restrict__ X,
    const int* __restrict__ off, const unsigned short* __restrict__ csr,
    const unsigned short* __restrict__ Wf1, const void* __restrict__ bias1,
    const unsigned short* __restrict__ Wf2, const void* __restrict__ bias2,
    unsigned short* __restrict__ Out, int M, const int* __restrict__ flagp,
    const int* __restrict__ batch, float* __restrict__ psum,
    unsigned int* __restrict__ pmax) {
    constexpr int KC1 = K1 / 32;
    __shared__ __align__(16) unsigned short lds_hi[64 * 136];
    __shared__ __align__(16) unsigned short lds_lo[64 * 136];
    __shared__ int batch_lds[64];

    int flag = *flagp;
    int wave = threadIdx.x >> 6;
    int lane = threadIdx.x & 63;
    int m_ = lane & 15;
    int q  = lane >> 4;

    if constexpr (POOL) {
        if (threadIdx.x < 64) {
            int gr = blockIdx.x * 64 + threadIdx.x;
            batch_lds[threadIdx.x] = gr < M ? batch[gr] : -1;
        }
    }

    // ================= gather phase (wave-private rows) =================
    int np = lane >> 4;      // node within pass (0..3)
    int l  = lane & 15;      // feat-lane within node
#pragma unroll 1
    for (int p = 0; p < 4; p++) {
        int nl = wave * 16 + p * 4 + np;           // node_local 0..63
        int node = blockIdx.x * 64 + nl;
        int nodec = node < M ? node : (M - 1);
        int s = off[nodec], e = off[nodec + 1];
        if constexpr (FROMX) {
            float a0, a1, a2, a3;
            float b0 = 0.f, b1 = 0.f, b2 = 0.f, b3 = 0.f;
            float c0 = 0.f, c1 = 0.f, c2 = 0.f, c3 = 0.f;
            float d0 = 0.f, d1 = 0.f, d2 = 0.f, d3 = 0.f;
            if (flag) {
                const float4* xp = (const float4*)X;
                float4 u = xp[(size_t)nodec * 16 + l];
                a0 = u.x; a1 = u.y; a2 = u.z; a3 = u.w;
                int i = s;
                for (; i + 7 < e; i += 8) {
                    float4 v0 = xp[(size_t)csr[i] * 16 + l];
                    float4 v1 = xp[(size_t)csr[i + 1] * 16 + l];
                    float4 v2 = xp[(size_t)csr[i + 2] * 16 + l];
                    float4 v3 = xp[(size_t)csr[i + 3] * 16 + l];
                    float4 v4 = xp[(size_t)csr[i + 4] * 16 + l];
                    float4 v5 = xp[(size_t)csr[i + 5] * 16 + l];
                    float4 v6 = xp[(size_t)csr[i + 6] * 16 + l];
                    float4 v7 = xp[(size_t)csr[i + 7] * 16 + l];
                    a0 += v0.x; a1 += v0.y; a2 += v0.z; a3 += v0.w;
                    b0 += v1.x; b1 += v1.y; b2 += v1.z; b3 += v1.w;
                    c0 += v2.x; c1 += v2.y; c2 += v2.z; c3 += v2.w;
                    d0 += v3.x; d1 += v3.y; d2 += v3.z; d3 += v3.w;
                    a0 += v4.x; a1 += v4.y; a2 += v4.z; a3 += v4.w;
                    b0 += v5.x; b1 += v5.y; b2 += v5.z; b3 += v5.w;
                    c0 += v6.x; c1 += v6.y; c2 += v6.z; c3 += v6.w;
                    d0 += v7.x; d1 += v7.y; d2 += v7.z; d3 += v7.w;
                }
                for (; i + 3 < e; i += 4) {
                    float4 v0 = xp[(size_t)csr[i] * 16 + l];
                    float4 v1 = xp[(size_t)csr[i + 1] * 16 + l];
                    float4 v2 = xp[(size_t)csr[i + 2] * 16 + l];
                    float4 v3 = xp[(size_t)csr[i + 3] * 16 + l];
                    a0 += v0.x; a1 += v0.y; a2 += v0.z; a3 += v0.w;
                    b0 += v1.x; b1 += v1.y; b2 += v1.z; b3 += v1.w;
                    c0 += v2.x; c1 += v2.y; c2 += v2.z; c3 += v2.w;
                    d0 += v3.x; d1 += v3.y; d2 += v3.z; d3 += v3.w;
                }
                for (; i < e; i++) {
                    float4 v = xp[(size_t)csr[i] * 16 + l];
                    a0 += v.x; a1 += v.y; a2 += v.z; a3 += v.w;
                }
            } else {
                const ushort4* xp = (const ushort4*)X;
                ushort4 u = xp[(size_t)nodec * 16 + l];
                a0 = b2f(u.x); a1 = b2f(u.y); a2 = b2f(u.z); a3 = b2f(u.w);
                int i = s;
                for (; i + 7 < e; i += 8) {
                    ushort4 v0 = xp[(size_t)csr[i] * 16 + l];
                    ushort4 v1 = xp[(size_t)csr[i + 1] * 16 + l];
                    ushort4 v2 = xp[(size_t)csr[i + 2] * 16 + l];
                    ushort4 v3 = xp[(size_t)csr[i + 3] * 16 + l];
                    ushort4 v4 = xp[(size_t)csr[i + 4] * 16 + l];
                    ushort4 v5 = xp[(size_t)csr[i + 5] * 16 + l];
                    ushort4 v6 = xp[(size_t)csr[i + 6] * 16 + l];
                    ushort4 v7 = xp[(size_t)csr[i + 7] * 16 + l];
                    a0 += b2f(v0.x); a1 += b2f(v0.y); a2 += b2f(v0.z); a3 += b2f(v0.w);
                    b0 += b2f(v1.x); b1 += b2f(v1.y); b2 += b2f(v1.z); b3 += b2f(v1.w);
                    c0 += b2f(v2.x); c1 += b2f(v2.y); c2 += b2f(v2.z); c3 += b2f(v2.w);
                    d0 += b2f(v3.x); d1 += b2f(v3.y); d2 += b2f(v3.z); d3 += b2f(v3.w);
                    a0 += b2f(v4.x); a1 += b2f(v4.y); a2 += b2f(v4.z); a3 += b2f(v4.w);
                    b0 += b2f(v5.x); b1 += b2f(v5.y); b2 += b2f(v5.z); b3 += b2f(v5.w);
                    c0 += b2f(v6.x); c1 += b2f(v6.y); c2 += b2f(v6.z); c3 += b2f(v6.w);
                    d0 += b2f(v7.x); d1 += b2f(v7.y); d2 += b2f(v7.z); d3 += b2f(v7.w);
                }
                for (; i + 3 < e; i += 4) {
                    ushort4 v0 = xp[(size_t)csr[i] * 16 + l];
                    ushort4 v1 = xp[(size_t)csr[i + 1] * 16 + l];
                    ushort4 v2 = xp[(size_t)csr[i + 2] * 16 + l];
                    ushort4 v3 = xp[(size_t)csr[i + 3] * 16 + l];
                    a0 += b2f(v0.x); a1 += b2f(v0.y); a2 += b2f(v0.z); a3 += b2f(v0.w);
                    b0 += b2f(v1.x); b1 += b2f(v1.y); b2 += b2f(v1.z); b3 += b2f(v1.w);
                    c0 += b2f(v2.x); c1 += b2f(v2.y); c2 += b2f(v2.z); c3 += b2f(v2.w);
                    d0 += b2f(v3.x); d1 += b2f(v3.y); d2 += b2f(v3.z); d3 += b2f(v3.w);
                }
                for (; i < e; i++) {
                    ushort4 v = xp[(size_t)csr[i] * 16 + l];
                    a0 += b2f(v.x); a1 += b2f(v.y); a2 += b2f(v.z); a3 += b2f(v.w);
                }
            }
            ushort4 o;
            o.x = f2b(a0 + b0 + c0 + d0);
            o.y = f2b(a1 + b1 + c1 + d1);
            o.z = f2b(a2 + b2 + c2 + d2);
            o.w = f2b(a3 + b3 + c3 + d3);
            *reinterpret_cast<ushort4*>(&lds_hi[nl * 136 + l * 4]) = o;
        } else {
            const u16x8* hp = (const u16x8*)X;
            u16x8 u = hp[(size_t)nodec * 16 + l];
            float a[8], b[8], c[8], d[8];
#pragma unroll
            for (int j = 0; j < 8; j++) { a[j] = b2f(u[j]); b[j] = 0.f; c[j] = 0.f; d[j] = 0.f; }
            int i = s;
            for (; i + 7 < e; i += 8) {
                u16x8 v0 = hp[(size_t)csr[i] * 16 + l];
                u16x8 v1 = hp[(size_t)csr[i + 1] * 16 + l];
                u16x8 v2 = hp[(size_t)csr[i + 2] * 16 + l];
                u16x8 v3 = hp[(size_t)csr[i + 3] * 16 + l];
                u16x8 v4 = hp[(size_t)csr[i + 4] * 16 + l];
                u16x8 v5 = hp[(size_t)csr[i + 5] * 16 + l];
                u16x8 v6 = hp[(size_t)csr[i + 6] * 16 + l];
                u16x8 v7 = hp[(size_t)csr[i + 7] * 16 + l];
#pragma unroll
                for (int j = 0; j < 8; j++) {
                    a[j] += b2f(v0[j]); b[j] += b2f(v1[j]);
                    c[j] += b2f(v2[j]); d[j] += b2f(v3[j]);
                }
#pragma unroll
                for (int j = 0; j < 8; j++) {
                    a[j] += b2f(v4[j]); b[j] += b2f(v5[j]);
                    c[j] += b2f(v6[j]); d[j] += b2f(v7[j]);
                }
            }
            for (; i + 3 < e; i += 4) {
                u16x8 v0 = hp[(size_t)csr[i] * 16 + l];
                u16x8 v1 = hp[(size_t)csr[i + 1] * 16 + l];
                u16x8 v2 = hp[(size_t)csr[i + 2] * 16 + l];
                u16x8 v3 = hp[(size_t)csr[i + 3] * 16 + l];
#pragma unroll
                for (int j = 0; j < 8; j++) {
                    a[j] += b2f(v0[j]); b[j] += b2f(v1[j]);
                    c[j] += b2f(v2[j]); d[j] += b2f(v3[j]);
                }
            }
            for (; i < e; i++) {
                u16x8 v = hp[(size_t)csr[i] * 16 + l];
#pragma unroll
                for (int j = 0; j < 8; j++) a[j] += b2f(v[j]);
            }
            u16x8 o;
#pragma unroll
            for (int j = 0; j < 8; j++) o[j] = f2b(a[j] + b[j] + c[j] + d[j]);
            *reinterpret_cast<u16x8*>(&lds_hi[nl * 136 + l * 8]) = o;
        }
    }

    // ================= MFMA phase (A-frags from LDS) =================
    const unsigned short* wfl1 = Wf1 + lane * 8;
    const unsigned short* wfl2 = Wf2 + lane * 8;
    const unsigned short* zlds = &lds_hi[(wave * 16 + m_) * 136 + q * 8];

    bf16x8 afrag[KC1];
#pragma unroll
    for (int c = 0; c < KC1; c++)
        afrag[c] = *reinterpret_cast<const bf16x8*>(zlds + c * 32);

    float b1v[8], b2v[8];
#pragma unroll
    for (int t = 0; t < 8; t++) {
        int col = t * 16 + m_;
        b1v[t] = flag ? ((const float*)bias1)[col]
                      : b2f(((const unsigned short*)bias1)[col]);
        b2v[t] = flag ? ((const float*)bias2)[col]
                      : b2f(((const unsigned short*)bias2)[col]);
    }

    f32x4 acc[8];
#pragma unroll
    for (int t = 0; t < 8; t++) acc[t] = (f32x4)(0.0f);

    // phase 1: mid = Z @ W1, weights double-buffered 8 fragments wide
    {
        bf16x8 wb[8], wn[8];
#pragma unroll
        for (int t = 0; t < 8; t++)
            wb[t] = *reinterpret_cast<const bf16x8*>(wfl1 + ((t * KC1 + 0) << 9));
#pragma unroll
        for (int c = 0; c < KC1; c++) {
            if (c + 1 < KC1) {
#pragma unroll
                for (int t = 0; t < 8; t++)
                    wn[t] = *reinterpret_cast<const bf16x8*>(wfl1 + ((t * KC1 + c + 1) << 9));
            }
#pragma unroll
            for (int t = 0; t < 8; t++)
                acc[t] = __builtin_amdgcn_mfma_f32_16x16x32_bf16(afrag[c], wb[t], acc[t], 0, 0, 0);
            if (c + 1 < KC1) {
#pragma unroll
                for (int t = 0; t < 8; t++) wb[t] = wn[t];
            }
        }
    }

    // epilogue 1: +b1, relu, hi/lo split -> LDS
#pragma unroll
    for (int r = 0; r < 4; r++) {
        int lr = wave * 16 + q * 4 + r;
#pragma unroll
        for (int t = 0; t < 8; t++) {
            int col = t * 16 + m_;
            float v = acc[t][r] + b1v[t];
            v = v > 0.0f ? v : 0.0f;
            unsigned short hb = f2b(v);
            lds_hi[lr * 136 + col] = hb;
            lds_lo[lr * 136 + col] = f2b(v - b2f(hb));
        }
    }

#pragma unroll
    for (int t = 0; t < 8; t++) acc[t] = (f32x4)(0.0f);

    // phase 2: h = mid @ W2 (hi/lo from LDS), weights double-buffered
    {
        int lr2 = wave * 16 + m_;
        const unsigned short* hibase = &lds_hi[lr2 * 136 + q * 8];
        const unsigned short* lobase = &lds_lo[lr2 * 136 + q * 8];
        bf16x8 wb[8], wn[8];
#pragma unroll
        for (int t = 0; t < 8; t++)
            wb[t] = *reinterpret_cast<const bf16x8*>(wfl2 + ((t * 4 + 0) << 9));
#pragma unroll
        for (int c = 0; c < 4; c++) {
            if (c < 3) {
#pragma unroll
                for (int t = 0; t < 8; t++)
                    wn[t] = *reinterpret_cast<const bf16x8*>(wfl2 + ((t * 4 + c + 1) << 9));
            }
            bf16x8 ahi = *reinterpret_cast<const bf16x8*>(hibase + c * 32);
            bf16x8 alo = *reinterpret_cast<const bf16x8*>(lobase + c * 32);
#pragma unroll
            for (int t = 0; t < 8; t++) {
                acc[t] = __builtin_amdgcn_mfma_f32_16x16x32_bf16(ahi, wb[t], acc[t], 0, 0, 0);
                acc[t] = __builtin_amdgcn_mfma_f32_16x16x32_bf16(alo, wb[t], acc[t], 0, 0, 0);
            }
            if (c < 3) {
#pragma unroll
                for (int t = 0; t < 8; t++) wb[t] = wn[t];
            }
        }
    }

    // epilogue 2
#pragma unroll
    for (int r = 0; r < 4; r++) {
        int lr = wave * 16 + q * 4 + r;
        int orow = blockIdx.x * 64 + lr;
#pragma unroll
        for (int t = 0; t < 8; t++) {
            int col = t * 16 + m_;
            float v = acc[t][r] + b2v[t];
            v = v > 0.0f ? v : 0.0f;
            if constexpr (POOL) {
                lds_hi[lr * 136 + col] = f2b(v);   // safe: own rows' phase-2 reads done
            } else {
                if (orow < M) Out[(size_t)orow * HID + col] = f2b(v);
            }
        }
    }

    if constexpr (POOL) {
        __syncthreads();
        int f = threadIdx.x;
        if (f < HID) {
            int cur = -1;
            float sum = 0.0f, mx = 0.0f;
            for (int rrow = 0; rrow < 64; rrow++) {
                int g = batch_lds[rrow];
                if (g < 0) break;   // tail padding
                float v = b2f(lds_hi[rrow * 136 + f]);
                if (g == cur) {
                    sum += v;
                    mx = fmaxf(mx, v);
                } else {
                    if (cur >= 0) {
                        atomicAdd(&psum[cur * HID + f], sum);
                        atomicMax(&pmax[cur * HID + f], __float_as_uint(mx));
                    }
                    cur = g; sum = v; mx = v;
                }
            }
            if (cur >= 0) {
                atomicAdd(&psum[cur * HID + f], sum);
                atomicMax(&pmax[cur * HID + f], __float_as_uint(mx));
            }
        }
    }
}

// ---------------- head: w1t[n][k] bf16 rows -> vectorized, unrolled dot ----------------
__global__ __launch_bounds__(128) void head_kernel(
    const float* __restrict__ psum, const unsigned int* __restrict__ pmax,
    const int* __restrict__ gstart,
    const unsigned short* __restrict__ w1t,
    const void* __restrict__ b1, const void* __restrict__ w2,
    const void* __restrict__ b2,
    void* __restrict__ out, const int* __restrict__ flagp) {
    int g = blockIdx.x;
    int n = threadIdx.x;
    int flag = *flagp;
    __shared__ float repr[2 * HID];
    __shared__ float red[HID];

    float c = (float)(gstart[g + 1] - gstart[g]);
    float inv = 1.0f / fmaxf(c, 1.0f);
    repr[n]       = psum[g * HID + n] * inv;
    repr[HID + n] = __uint_as_float(pmax[g * HID + n]);
    __syncthreads();

    const u16x8* wp = (const u16x8*)(w1t + n * 256);
    float a0 = 0.f, a1 = 0.f, a2 = 0.f, a3 = 0.f;
#pragma unroll
    for (int c8 = 0; c8 < 32; c8 += 4) {
        u16x8 w0 = wp[c8 + 0];
        u16x8 w1 = wp[c8 + 1];
        u16x8 w2v = wp[c8 + 2];
        u16x8 w3 = wp[c8 + 3];
#pragma unroll
        for (int j = 0; j < 8; j++) {
            a0 += repr[(c8 + 0) * 8 + j] * b2f(w0[j]);
            a1 += repr[(c8 + 1) * 8 + j] * b2f(w1[j]);
            a2 += repr[(c8 + 2) * 8 + j] * b2f(w2v[j]);
            a3 += repr[(c8 + 3) * 8 + j] * b2f(w3[j]);
        }
    }
    float b1v = flag ? ((const float*)b1)[n] : b2f(((const unsigned short*)b1)[n]);
    float acc = a0 + a1 + a2 + a3 + b1v;
    acc = fmaxf(acc, 0.0f);

    float w2s = flag ? ((const float*)w2)[n] : b2f(((const unsigned short*)w2)[n]);
    red[n] = acc * w2s;
    __syncthreads();
    for (int s = 64; s > 0; s >>= 1) {
        if (n < s) red[n] += red[n + s];
        __syncthreads();
    }
    if (n == 0) {
        float b2v = flag ? ((const float*)b2)[0] : b2f(((const unsigned short*)b2)[0]);
        float logit = red[0] + b2v;
        float sv = 1.0f / (1.0f + expf(-logit));
        if (flag) ((float*)out)[g] = sv;
        else      ((unsigned short*)out)[g] = f2b(sv);
    }
}

extern "C" void kernel_launch(void* const* d_in, const int* in_sizes, int n_in,
                              void* d_out, int out_size, void* d_ws, size_t ws_size,
                              hipStream_t stream) {
    const int* edge = (const int*)d_in[1];
    const int* srcv = edge;
    const int* dstv = edge + N_EDGES;
    const int* batch = (const int*)d_in[2];

    char* ws = (char*)d_ws;
    unsigned short* A = (unsigned short*)ws;               // 12.8 MB bf16 h (even)
    unsigned short* B = (unsigned short*)(ws + 12800000);  // 12.8 MB bf16 h (odd)
    unsigned int* ebuf = (unsigned int*)(ws + 25600000);   // 6.43 MB bucketed edges
    unsigned short* csr = (unsigned short*)(ws + 32100000);// 1.6 MB
    int* off    = (int*)(ws + 33700000);                   // 50001 ints
    unsigned short* wfbase = (unsigned short*)(ws + 33904000);  // 6 x 32 KB
    float* psum  = (float*)(ws + 34100608);                // 128 KB
    unsigned int* pmax = (unsigned int*)(ws + 34231680);   // 128 KB
    int* gstart  = (int*)(ws + 34363776);                  // 2 KB
    int* flagp   = (int*)(ws + 34365824);
    unsigned short* w1t = (unsigned short*)(ws + 34366848); // 64 KB
    int* bcursor = (int*)(ws + 34432384);                  // padded: 196 x 64 B = 12.5 KB

    const size_t NEED = 34500000;
    if (ws_size < NEED) {
        unsigned int k = 0;
        while ((((size_t)1) << (k + 1)) <= ws_size && k < 62) k++;
        diag_kernel<<<1, 256, 0, stream>>>((unsigned short*)d_out,
                                           (unsigned short)(0x4000 | (k & 63)));
        return;
    }

    mega_pre_kernel<<<581, 256, 0, stream>>>(
        (const unsigned short*)d_in[0],
        d_in[3], d_in[5], d_in[7], d_in[9], d_in[11], d_in[13], wfbase,
        batch, gstart, psum, pmax, d_in[15], w1t, bcursor, flagp);

    // CSR build: scatter into fixed buckets, then per-bucket sort
    const int EB = (N_EDGES + 4095) / 4096;   // 196
    bscatter_kernel<<<EB, 1024, 0, stream>>>(srcv, dstv, bcursor, ebuf);
    bsort_kernel<<<NBUCK, 512, 0, stream>>>(ebuf, bcursor, off, csr);

    const int GEMM_GRID = (N_NODES + 63) / 64;   // 782

    // layer 0: x -> A (fused gather_x + MLP0)
    fused_gin_kernel<64, false, true><<<GEMM_GRID, 256, 0, stream>>>(
        d_in[0], off, csr,
        wfbase + 0 * 16384, d_in[4], wfbase + 1 * 16384, d_in[6],
        A, N_NODES, flagp, batch, psum, pmax);

    // layer 1: A -> B (fused gather128 + MLP1)
    fused_gin_kernel<128, false, false><<<GEMM_GRID, 256, 0, stream>>>(
        A, off, csr,
        wfbase + 2 * 16384, d_in[8], wfbase + 3 * 16384, d_in[10],
        B, N_NODES, flagp, batch, psum, pmax);

    // layer 2: B -> pooled directly (fused gather128 + MLP2 + pool)
    fused_gin_kernel<128, true, false><<<GEMM_GRID, 256, 0, stream>>>(
        B, off, csr,
        wfbase + 4 * 16384, d_in[12], wfbase + 5 * 16384, d_in[14],
        A /*unused*/, N_NODES, flagp, batch, psum, pmax);

    // head
    head_kernel<<<NUM_GRAPHS, 128, 0, stream>>>(psum, pmax, gstart, w1t,
                                                d_in[16], d_in[17], d_in[18],
                                                d_out, flagp);
}

// Round 9
// 247.300 us; speedup vs baseline: 1.2558x; 1.0054x over previous
//
#include <hip/hip_runtime.h>
#include <hip/hip_bf16.h>

#define N_NODES   50000
#define N_EDGES   800000
#define IN_DIM    64
#define HID       128
#define NUM_GRAPHS 256
#define NBUCK     196     // ceil(50000/256) buckets of 256 nodes
#define BCAP      8192    // fixed ebuf capacity per bucket (avg fill 4082)
#define CPAD      16      // bcursor padding: 16 ints = 64 B per counter

typedef __bf16 bf16x8 __attribute__((ext_vector_type(8)));
typedef unsigned short u16x8 __attribute__((ext_vector_type(8)));
typedef float f32x4 __attribute__((ext_vector_type(4)));

__device__ __forceinline__ float b2f(unsigned short u) {
    return __uint_as_float(((unsigned int)u) << 16);
}
__device__ __forceinline__ unsigned short f2b(float f) {
    unsigned int x = __float_as_uint(f);
    x = (x + 0x7fffu + ((x >> 16) & 1u)) >> 16;   // RNE
    return (unsigned short)x;
}

__global__ void diag_kernel(unsigned short* out, unsigned short pat) {
    out[threadIdx.x] = pat;
}

// ---------------- mega preprocess ----------------
// blocks 0..351: GIN weight reorder; 352..547: graph ranges + pool zero;
// 548..579: head_w1 transpose -> w1t[n][k] bf16; 580: dtype probe + bucket cursor init
__global__ __launch_bounds__(256) void mega_pre_kernel(
    const unsigned short* __restrict__ x,
    const void* w0, const void* w1, const void* w2,
    const void* w3, const void* w4, const void* w5,
    unsigned short* __restrict__ wfbase,
    const int* __restrict__ batch, int* __restrict__ gstart,
    float* __restrict__ psum, unsigned int* __restrict__ pmax,
    const void* hw1, unsigned short* __restrict__ w1t,
    int* __restrict__ bcursor, int* __restrict__ flagp) {
    int b = blockIdx.x;
    int tid = threadIdx.x;

    if (b < 352) {
        __shared__ int cnt;
        if (tid == 0) cnt = 0;
        __syncthreads();
        unsigned short u = x[2 * tid];
        int e = (u >> 7) & 0xff;
        if (e <= 100 || e >= 140) atomicAdd(&cnt, 1);
        __syncthreads();
        int flag = cnt > 64;   // 1 = fp32, 0 = bf16

        int mat, boff;
        if (b < 32) { mat = 0; boff = b; }
        else { mat = 1 + (b - 32) / 64; boff = (b - 32) % 64; }
        const void* W = mat == 0 ? w0 : mat == 1 ? w1 : mat == 2 ? w2
                      : mat == 3 ? w3 : mat == 4 ? w4 : w5;
        int KC = (mat == 0) ? 2 : 4;
        int idx = boff * 256 + tid;
        int j  = idx & 7;
        int l  = (idx >> 3) & 63;
        int tc = idx >> 9;
        int c  = tc % KC;
        int t  = tc / KC;
        int k  = c * 32 + (l >> 4) * 8 + j;
        int n  = t * 16 + (l & 15);
        unsigned short v = flag ? f2b(((const float*)W)[k * 128 + n])
                                : ((const unsigned short*)W)[k * 128 + n];
        wfbase[mat * 16384 + idx] = v;
    } else if (b < 548) {
        int i = (b - 352) * 256 + tid;
        if (i < NUM_GRAPHS * HID) { psum[i] = 0.0f; pmax[i] = 0u; }
        if (i >= N_NODES) return;
        int b1 = batch[i];
        int b0 = (i == 0) ? -1 : batch[i - 1];
        for (int g = b0 + 1; g <= b1; g++) gstart[g] = i;
        if (i == N_NODES - 1)
            for (int g = b1 + 1; g <= NUM_GRAPHS; g++) gstart[g] = N_NODES;
    } else if (b < 580) {
        // head_w1 transpose: w1t[n*256 + k] = hw1[k*128 + n], bf16
        __shared__ int cnt;
        if (tid == 0) cnt = 0;
        __syncthreads();
        unsigned short u = x[2 * tid];
        int e = (u >> 7) & 0xff;
        if (e <= 100 || e >= 140) atomicAdd(&cnt, 1);
        __syncthreads();
        int flag = cnt > 64;
        int base = (b - 548) * 1024;
#pragma unroll
        for (int j = 0; j < 4; j++) {
            int idx = base + j * 256 + tid;   // [0, 32768)
            int n = idx >> 8;
            int k = idx & 255;
            unsigned short v = flag ? f2b(((const float*)hw1)[k * 128 + n])
                                    : ((const unsigned short*)hw1)[k * 128 + n];
            w1t[idx] = v;
        }
    } else {
        if (tid < NBUCK) bcursor[tid * CPAD] = tid * BCAP;   // padded: 1 counter / 64B line
        __shared__ int cnt;
        if (tid == 0) cnt = 0;
        __syncthreads();
        int c = 0;
        for (int j = 0; j < 16; j++) {
            unsigned short u = x[2 * (tid * 16 + j)];
            int e = (u >> 7) & 0xff;
            if (e <= 100 || e >= 140) c++;
        }
        atomicAdd(&cnt, c);
        __syncthreads();
        if (tid == 0) *flagp = (cnt > 1024) ? 1 : 0;
    }
}

// ---------------- CSR build: scatter into fixed-capacity bucket regions ----------------
__global__ __launch_bounds__(1024) void bscatter_kernel(const int* __restrict__ src,
        const int* __restrict__ dst, int* __restrict__ bcursor,
        unsigned int* __restrict__ ebuf) {
    __shared__ int lcnt[NBUCK];
    __shared__ int lbase[NBUCK];
    __shared__ int lcur[NBUCK];
    int tid = threadIdx.x;
    if (tid < NBUCK) lcnt[tid] = 0;
    __syncthreads();
    int e0 = blockIdx.x * 4096;
    int d[4], s[4];
#pragma unroll
    for (int k = 0; k < 4; k++) {
        int e = e0 + k * 1024 + tid;
        if (e < N_EDGES) {
            d[k] = dst[e]; s[k] = src[e];
            atomicAdd(&lcnt[d[k] >> 8], 1);
        } else d[k] = -1;
    }
    __syncthreads();
    if (tid < NBUCK) {
        int c = lcnt[tid];
        lbase[tid] = c ? atomicAdd(&bcursor[tid * CPAD], c) : 0;   // padded counters
        lcur[tid] = 0;
    }
    __syncthreads();
#pragma unroll
    for (int k = 0; k < 4; k++) {
        if (d[k] >= 0) {
            int b = d[k] >> 8;
            int p = lbase[b] + atomicAdd(&lcur[b], 1);
            ebuf[p] = ((unsigned int)(d[k] & 255) << 16) | (unsigned int)s[k];
        }
    }
}

// per-bucket counting sort -> compact off + csr. R9: 10-bit key =
// (dst_local<<2)|src_bucket so each node's adjacency list is ordered by
// source region (4 x 12500 nodes = 3.2 MB of h each, fits 4 MiB per-XCD L2).
// Co-resident gather waves then sweep source buckets roughly in phase ->
// L2 temporal locality, without any change to the gather kernel.
__global__ __launch_bounds__(1024) void bsort_kernel(const unsigned int* __restrict__ ebuf,
        const int* __restrict__ bcursor, int* __restrict__ off,
        unsigned short* __restrict__ csr) {
    __shared__ int cntA[256];
    __shared__ int scB[256];
    __shared__ int sc[1024];
    __shared__ int lcur[1024];
    int b = blockIdx.x, tid = threadIdx.x;

    // global 196-scan of per-bucket totals (from final cursors)
    if (tid < 256) {
        int v = (tid < NBUCK) ? (bcursor[tid * CPAD] - tid * BCAP) : 0;
        cntA[tid] = v;
        scB[tid] = v;
    }
    __syncthreads();
    for (int d = 1; d < 256; d <<= 1) {
        int t = (tid >= d && tid < 256) ? scB[tid - d] : 0;
        __syncthreads();
        if (tid < 256) scB[tid] += t;
        __syncthreads();
    }
    int base = scB[b] - cntA[b];   // exclusive prefix for this bucket
    int cnt  = cntA[b];
    int ebase = b * BCAP;
    __syncthreads();

    // count by 10-bit key
    sc[tid] = 0;
    __syncthreads();
    for (int i = tid; i < cnt; i += 1024) {
        unsigned int ev = ebuf[ebase + i];
        int s = (int)(ev & 0xffffu);
        int key = (int)((ev >> 16) << 2) |
                  ((s >= 12500) + (s >= 25000) + (s >= 37500));
        atomicAdd(&sc[key], 1);
    }
    __syncthreads();
    int v2 = sc[tid];
    __syncthreads();
    // inclusive scan over 1024 keys (in place)
    for (int d = 1; d < 1024; d <<= 1) {
        int t = (tid >= d) ? sc[tid - d] : 0;
        __syncthreads();
        sc[tid] += t;
        __syncthreads();
    }
    int excl = sc[tid] - v2;
    lcur[tid] = excl;
    if ((tid & 3) == 0) {
        int node = b * 256 + (tid >> 2);
        if (node < N_NODES) off[node] = base + excl;   // start of node = its bucket-0 start
    }
    if (b == 0 && tid == 0) off[N_NODES] = N_EDGES;
    __syncthreads();
    // scatter in key order
    for (int i = tid; i < cnt; i += 1024) {
        unsigned int ev = ebuf[ebase + i];
        int s = (int)(ev & 0xffffu);
        int key = (int)((ev >> 16) << 2) |
                  ((s >= 12500) + (s >= 25000) + (s >= 37500));
        int p = atomicAdd(&lcur[key], 1);
        csr[base + p] = (unsigned short)s;
    }
}

// ---------------- fused gather + GIN MLP (R7 best-known, unchanged) ----------------
template <int K1, bool POOL, bool FROMX>
__global__ __launch_bounds__(256, 3) void fused_gin_kernel(
    const void* __restrict__ X,
    const int* __restrict__ off, const unsigned short* __restrict__ csr,
    const unsigned short* __restrict__ Wf1, const void* __restrict__ bias1,
    const unsigned short* __restrict__ Wf2, const void* __restrict__ bias2,
    unsigned short* __restrict__ Out, int M, const int* __restrict__ flagp,
    const int* __restrict__ batch, float* __restrict__ psum,
    unsigned int* __restrict__ pmax) {
    constexpr int KC1 = K1 / 32;
    __shared__ __align__(16) unsigned short lds_hi[64 * 136];
    __shared__ __align__(16) unsigned short lds_lo[64 * 136];
    __shared__ int batch_lds[64];

    int flag = *flagp;
    int wave = threadIdx.x >> 6;
    int lane = threadIdx.x & 63;
    int m_ = lane & 15;
    int q  = lane >> 4;

    if constexpr (POOL) {
        if (threadIdx.x < 64) {
            int gr = blockIdx.x * 64 + threadIdx.x;
            batch_lds[threadIdx.x] = gr < M ? batch[gr] : -1;
        }
    }

    // ================= gather phase (wave-private rows) =================
    int np = lane >> 4;      // node within pass (0..3)
    int l  = lane & 15;      // feat-lane within node
#pragma unroll 1
    for (int p = 0; p < 4; p++) {
        int nl = wave * 16 + p * 4 + np;           // node_local 0..63
        int node = blockIdx.x * 64 + nl;
        int nodec = node < M ? node : (M - 1);
        int s = off[nodec], e = off[nodec + 1];
        if constexpr (FROMX) {
            float a0, a1, a2, a3;
            float b0 = 0.f, b1 = 0.f, b2 = 0.f, b3 = 0.f;
            float c0 = 0.f, c1 = 0.f, c2 = 0.f, c3 = 0.f;
            float d0 = 0.f, d1 = 0.f, d2 = 0.f, d3 = 0.f;
            if (flag) {
                const float4* xp = (const float4*)X;
                float4 u = xp[(size_t)nodec * 16 + l];
                a0 = u.x; a1 = u.y; a2 = u.z; a3 = u.w;
                int i = s;
                for (; i + 7 < e; i += 8) {
                    float4 v0 = xp[(size_t)csr[i] * 16 + l];
                    float4 v1 = xp[(size_t)csr[i + 1] * 16 + l];
                    float4 v2 = xp[(size_t)csr[i + 2] * 16 + l];
                    float4 v3 = xp[(size_t)csr[i + 3] * 16 + l];
                    float4 v4 = xp[(size_t)csr[i + 4] * 16 + l];
                    float4 v5 = xp[(size_t)csr[i + 5] * 16 + l];
                    float4 v6 = xp[(size_t)csr[i + 6] * 16 + l];
                    float4 v7 = xp[(size_t)csr[i + 7] * 16 + l];
                    a0 += v0.x; a1 += v0.y; a2 += v0.z; a3 += v0.w;
                    b0 += v1.x; b1 += v1.y; b2 += v1.z; b3 += v1.w;
                    c0 += v2.x; c1 += v2.y; c2 += v2.z; c3 += v2.w;
                    d0 += v3.x; d1 += v3.y; d2 += v3.z; d3 += v3.w;
                    a0 += v4.x; a1 += v4.y; a2 += v4.z; a3 += v4.w;
                    b0 += v5.x; b1 += v5.y; b2 += v5.z; b3 += v5.w;
                    c0 += v6.x; c1 += v6.y; c2 += v6.z; c3 += v6.w;
                    d0 += v7.x; d1 += v7.y; d2 += v7.z; d3 += v7.w;
                }
                for (; i + 3 < e; i += 4) {
                    float4 v0 = xp[(size_t)csr[i] * 16 + l];
                    float4 v1 = xp[(size_t)csr[i + 1] * 16 + l];
                    float4 v2 = xp[(size_t)csr[i + 2] * 16 + l];
                    float4 v3 = xp[(size_t)csr[i + 3] * 16 + l];
                    a0 += v0.x; a1 += v0.y; a2 += v0.z; a3 += v0.w;
                    b0 += v1.x; b1 += v1.y; b2 += v1.z; b3 += v1.w;
                    c0 += v2.x; c1 += v2.y; c2 += v2.z; c3 += v2.w;
                    d0 += v3.x; d1 += v3.y; d2 += v3.z; d3 += v3.w;
                }
                for (; i < e; i++) {
                    float4 v = xp[(size_t)csr[i] * 16 + l];
                    a0 += v.x; a1 += v.y; a2 += v.z; a3 += v.w;
                }
            } else {
                const ushort4* xp = (const ushort4*)X;
                ushort4 u = xp[(size_t)nodec * 16 + l];
                a0 = b2f(u.x); a1 = b2f(u.y); a2 = b2f(u.z); a3 = b2f(u.w);
                int i = s;
                for (; i + 7 < e; i += 8) {
                    ushort4 v0 = xp[(size_t)csr[i] * 16 + l];
                    ushort4 v1 = xp[(size_t)csr[i + 1] * 16 + l];
                    ushort4 v2 = xp[(size_t)csr[i + 2] * 16 + l];
                    ushort4 v3 = xp[(size_t)csr[i + 3] * 16 + l];
                    ushort4 v4 = xp[(size_t)csr[i + 4] * 16 + l];
                    ushort4 v5 = xp[(size_t)csr[i + 5] * 16 + l];
                    ushort4 v6 = xp[(size_t)csr[i + 6] * 16 + l];
                    ushort4 v7 = xp[(size_t)csr[i + 7] * 16 + l];
                    a0 += b2f(v0.x); a1 += b2f(v0.y); a2 += b2f(v0.z); a3 += b2f(v0.w);
                    b0 += b2f(v1.x); b1 += b2f(v1.y); b2 += b2f(v1.z); b3 += b2f(v1.w);
                    c0 += b2f(v2.x); c1 += b2f(v2.y); c2 += b2f(v2.z); c3 += b2f(v2.w);
                    d0 += b2f(v3.x); d1 += b2f(v3.y); d2 += b2f(v3.z); d3 += b2f(v3.w);
                    a0 += b2f(v4.x); a1 += b2f(v4.y); a2 += b2f(v4.z); a3 += b2f(v4.w);
                    b0 += b2f(v5.x); b1 += b2f(v5.y); b2 += b2f(v5.z); b3 += b2f(v5.w);
                    c0 += b2f(v6.x); c1 += b2f(v6.y); c2 += b2f(v6.z); c3 += b2f(v6.w);
                    d0 += b2f(v7.x); d1 += b2f(v7.y); d2 += b2f(v7.z); d3 += b2f(v7.w);
                }
                for (; i + 3 < e; i += 4) {
                    ushort4 v0 = xp[(size_t)csr[i] * 16 + l];
                    ushort4 v1 = xp[(size_t)csr[i + 1] * 16 + l];
                    ushort4 v2 = xp[(size_t)csr[i + 2] * 16 + l];
                    ushort4 v3 = xp[(size_t)csr[i + 3] * 16 + l];
                    a0 += b2f(v0.x); a1 += b2f(v0.y); a2 += b2f(v0.z); a3 += b2f(v0.w);
                    b0 += b2f(v1.x); b1 += b2f(v1.y); b2 += b2f(v1.z); b3 += b2f(v1.w);
                    c0 += b2f(v2.x); c1 += b2f(v2.y); c2 += b2f(v2.z); c3 += b2f(v2.w);
                    d0 += b2f(v3.x); d1 += b2f(v3.y); d2 += b2f(v3.z); d3 += b2f(v3.w);
                }
                for (; i < e; i++) {
                    ushort4 v = xp[(size_t)csr[i] * 16 + l];
                    a0 += b2f(v.x); a1 += b2f(v.y); a2 += b2f(v.z); a3 += b2f(v.w);
                }
            }
            ushort4 o;
            o.x = f2b(a0 + b0 + c0 + d0);
            o.y = f2b(a1 + b1 + c1 + d1);
            o.z = f2b(a2 + b2 + c2 + d2);
            o.w = f2b(a3 + b3 + c3 + d3);
            *reinterpret_cast<ushort4*>(&lds_hi[nl * 136 + l * 4]) = o;
        } else {
            const u16x8* hp = (const u16x8*)X;
            u16x8 u = hp[(size_t)nodec * 16 + l];
            float a[8], b[8], c[8], d[8];
#pragma unroll
            for (int j = 0; j < 8; j++) { a[j] = b2f(u[j]); b[j] = 0.f; c[j] = 0.f; d[j] = 0.f; }
            int i = s;
            for (; i + 7 < e; i += 8) {
                u16x8 v0 = hp[(size_t)csr[i] * 16 + l];
                u16x8 v1 = hp[(size_t)csr[i + 1] * 16 + l];
                u16x8 v2 = hp[(size_t)csr[i + 2] * 16 + l];
                u16x8 v3 = hp[(size_t)csr[i + 3] * 16 + l];
                u16x8 v4 = hp[(size_t)csr[i + 4] * 16 + l];
                u16x8 v5 = hp[(size_t)csr[i + 5] * 16 + l];
                u16x8 v6 = hp[(size_t)csr[i + 6] * 16 + l];
                u16x8 v7 = hp[(size_t)csr[i + 7] * 16 + l];
#pragma unroll
                for (int j = 0; j < 8; j++) {
                    a[j] += b2f(v0[j]); b[j] += b2f(v1[j]);
                    c[j] += b2f(v2[j]); d[j] += b2f(v3[j]);
                }
#pragma unroll
                for (int j = 0; j < 8; j++) {
                    a[j] += b2f(v4[j]); b[j] += b2f(v5[j]);
                    c[j] += b2f(v6[j]); d[j] += b2f(v7[j]);
                }
            }
            for (; i + 3 < e; i += 4) {
                u16x8 v0 = hp[(size_t)csr[i] * 16 + l];
                u16x8 v1 = hp[(size_t)csr[i + 1] * 16 + l];
                u16x8 v2 = hp[(size_t)csr[i + 2] * 16 + l];
                u16x8 v3 = hp[(size_t)csr[i + 3] * 16 + l];
#pragma unroll
                for (int j = 0; j < 8; j++) {
                    a[j] += b2f(v0[j]); b[j] += b2f(v1[j]);
                    c[j] += b2f(v2[j]); d[j] += b2f(v3[j]);
                }
            }
            for (; i < e; i++) {
                u16x8 v = hp[(size_t)csr[i] * 16 + l];
#pragma unroll
                for (int j = 0; j < 8; j++) a[j] += b2f(v[j]);
            }
            u16x8 o;
#pragma unroll
            for (int j = 0; j < 8; j++) o[j] = f2b(a[j] + b[j] + c[j] + d[j]);
            *reinterpret_cast<u16x8*>(&lds_hi[nl * 136 + l * 8]) = o;
        }
    }

    // ================= MFMA phase (A-frags from LDS) =================
    const unsigned short* wfl1 = Wf1 + lane * 8;
    const unsigned short* wfl2 = Wf2 + lane * 8;
    const unsigned short* zlds = &lds_hi[(wave * 16 + m_) * 136 + q * 8];

    bf16x8 afrag[KC1];
#pragma unroll
    for (int c = 0; c < KC1; c++)
        afrag[c] = *reinterpret_cast<const bf16x8*>(zlds + c * 32);

    float b1v[8], b2v[8];
#pragma unroll
    for (int t = 0; t < 8; t++) {
        int col = t * 16 + m_;
        b1v[t] = flag ? ((const float*)bias1)[col]
                      : b2f(((const unsigned short*)bias1)[col]);
        b2v[t] = flag ? ((const float*)bias2)[col]
                      : b2f(((const unsigned short*)bias2)[col]);
    }

    f32x4 acc[8];
#pragma unroll
    for (int t = 0; t < 8; t++) acc[t] = (f32x4)(0.0f);

    // phase 1: mid = Z @ W1, weights double-buffered 8 fragments wide
    {
        bf16x8 wb[8], wn[8];
#pragma unroll
        for (int t = 0; t < 8; t++)
            wb[t] = *reinterpret_cast<const bf16x8*>(wfl1 + ((t * KC1 + 0) << 9));
#pragma unroll
        for (int c = 0; c < KC1; c++) {
            if (c + 1 < KC1) {
#pragma unroll
                for (int t = 0; t < 8; t++)
                    wn[t] = *reinterpret_cast<const bf16x8*>(wfl1 + ((t * KC1 + c + 1) << 9));
            }
#pragma unroll
            for (int t = 0; t < 8; t++)
                acc[t] = __builtin_amdgcn_mfma_f32_16x16x32_bf16(afrag[c], wb[t], acc[t], 0, 0, 0);
            if (c + 1 < KC1) {
#pragma unroll
                for (int t = 0; t < 8; t++) wb[t] = wn[t];
            }
        }
    }

    // epilogue 1: +b1, relu, hi/lo split -> LDS
#pragma unroll
    for (int r = 0; r < 4; r++) {
        int lr = wave * 16 + q * 4 + r;
#pragma unroll
        for (int t = 0; t < 8; t++) {
            int col = t * 16 + m_;
            float v = acc[t][r] + b1v[t];
            v = v > 0.0f ? v : 0.0f;
            unsigned short hb = f2b(v);
            lds_hi[lr * 136 + col] = hb;
            lds_lo[lr * 136 + col] = f2b(v - b2f(hb));
        }
    }

#pragma unroll
    for (int t = 0; t < 8; t++) acc[t] = (f32x4)(0.0f);

    // phase 2: h = mid @ W2 (hi/lo from LDS), weights double-buffered
    {
        int lr2 = wave * 16 + m_;
        const unsigned short* hibase = &lds_hi[lr2 * 136 + q * 8];
        const unsigned short* lobase = &lds_lo[lr2 * 136 + q * 8];
        bf16x8 wb[8], wn[8];
#pragma unroll
        for (int t = 0; t < 8; t++)
            wb[t] = *reinterpret_cast<const bf16x8*>(wfl2 + ((t * 4 + 0) << 9));
#pragma unroll
        for (int c = 0; c < 4; c++) {
            if (c < 3) {
#pragma unroll
                for (int t = 0; t < 8; t++)
                    wn[t] = *reinterpret_cast<const bf16x8*>(wfl2 + ((t * 4 + c + 1) << 9));
            }
            bf16x8 ahi = *reinterpret_cast<const bf16x8*>(hibase + c * 32);
            bf16x8 alo = *reinterpret_cast<const bf16x8*>(lobase + c * 32);
#pragma unroll
            for (int t = 0; t < 8; t++) {
                acc[t] = __builtin_amdgcn_mfma_f32_16x16x32_bf16(ahi, wb[t], acc[t], 0, 0, 0);
                acc[t] = __builtin_amdgcn_mfma_f32_16x16x32_bf16(alo, wb[t], acc[t], 0, 0, 0);
            }
            if (c < 3) {
#pragma unroll
                for (int t = 0; t < 8; t++) wb[t] = wn[t];
            }
        }
    }

    // epilogue 2
#pragma unroll
    for (int r = 0; r < 4; r++) {
        int lr = wave * 16 + q * 4 + r;
        int orow = blockIdx.x * 64 + lr;
#pragma unroll
        for (int t = 0; t < 8; t++) {
            int col = t * 16 + m_;
            float v = acc[t][r] + b2v[t];
            v = v > 0.0f ? v : 0.0f;
            if constexpr (POOL) {
                lds_hi[lr * 136 + col] = f2b(v);   // safe: own rows' phase-2 reads done
            } else {
                if (orow < M) Out[(size_t)orow * HID + col] = f2b(v);
            }
        }
    }

    if constexpr (POOL) {
        __syncthreads();
        int f = threadIdx.x;
        if (f < HID) {
            int cur = -1;
            float sum = 0.0f, mx = 0.0f;
            for (int rrow = 0; rrow < 64; rrow++) {
                int g = batch_lds[rrow];
                if (g < 0) break;   // tail padding
                float v = b2f(lds_hi[rrow * 136 + f]);
                if (g == cur) {
                    sum += v;
                    mx = fmaxf(mx, v);
                } else {
                    if (cur >= 0) {
                        atomicAdd(&psum[cur * HID + f], sum);
                        atomicMax(&pmax[cur * HID + f], __float_as_uint(mx));
                    }
                    cur = g; sum = v; mx = v;
                }
            }
            if (cur >= 0) {
                atomicAdd(&psum[cur * HID + f], sum);
                atomicMax(&pmax[cur * HID + f], __float_as_uint(mx));
            }
        }
    }
}

// ---------------- head: w1t[n][k] bf16 rows -> vectorized, unrolled dot ----------------
__global__ __launch_bounds__(128) void head_kernel(
    const float* __restrict__ psum, const unsigned int* __restrict__ pmax,
    const int* __restrict__ gstart,
    const unsigned short* __restrict__ w1t,
    const void* __restrict__ b1, const void* __restrict__ w2,
    const void* __restrict__ b2,
    void* __restrict__ out, const int* __restrict__ flagp) {
    int g = blockIdx.x;
    int n = threadIdx.x;
    int flag = *flagp;
    __shared__ float repr[2 * HID];
    __shared__ float red[HID];

    float c = (float)(gstart[g + 1] - gstart[g]);
    float inv = 1.0f / fmaxf(c, 1.0f);
    repr[n]       = psum[g * HID + n] * inv;
    repr[HID + n] = __uint_as_float(pmax[g * HID + n]);
    __syncthreads();

    const u16x8* wp = (const u16x8*)(w1t + n * 256);
    float a0 = 0.f, a1 = 0.f, a2 = 0.f, a3 = 0.f;
#pragma unroll
    for (int c8 = 0; c8 < 32; c8 += 4) {
        u16x8 w0 = wp[c8 + 0];
        u16x8 w1 = wp[c8 + 1];
        u16x8 w2v = wp[c8 + 2];
        u16x8 w3 = wp[c8 + 3];
#pragma unroll
        for (int j = 0; j < 8; j++) {
            a0 += repr[(c8 + 0) * 8 + j] * b2f(w0[j]);
            a1 += repr[(c8 + 1) * 8 + j] * b2f(w1[j]);
            a2 += repr[(c8 + 2) * 8 + j] * b2f(w2v[j]);
            a3 += repr[(c8 + 3) * 8 + j] * b2f(w3[j]);
        }
    }
    float b1v = flag ? ((const float*)b1)[n] : b2f(((const unsigned short*)b1)[n]);
    float acc = a0 + a1 + a2 + a3 + b1v;
    acc = fmaxf(acc, 0.0f);

    float w2s = flag ? ((const float*)w2)[n] : b2f(((const unsigned short*)w2)[n]);
    red[n] = acc * w2s;
    __syncthreads();
    for (int s = 64; s > 0; s >>= 1) {
        if (n < s) red[n] += red[n + s];
        __syncthreads();
    }
    if (n == 0) {
        float b2v = flag ? ((const float*)b2)[0] : b2f(((const unsigned short*)b2)[0]);
        float logit = red[0] + b2v;
        float sv = 1.0f / (1.0f + expf(-logit));
        if (flag) ((float*)out)[g] = sv;
        else      ((unsigned short*)out)[g] = f2b(sv);
    }
}

extern "C" void kernel_launch(void* const* d_in, const int* in_sizes, int n_in,
                              void* d_out, int out_size, void* d_ws, size_t ws_size,
                              hipStream_t stream) {
    const int* edge = (const int*)d_in[1];
    const int* srcv = edge;
    const int* dstv = edge + N_EDGES;
    const int* batch = (const int*)d_in[2];

    char* ws = (char*)d_ws;
    unsigned short* A = (unsigned short*)ws;               // 12.8 MB bf16 h (even)
    unsigned short* B = (unsigned short*)(ws + 12800000);  // 12.8 MB bf16 h (odd)
    unsigned int* ebuf = (unsigned int*)(ws + 25600000);   // 6.43 MB bucketed edges
    unsigned short* csr = (unsigned short*)(ws + 32100000);// 1.6 MB
    int* off    = (int*)(ws + 33700000);                   // 50001 ints
    unsigned short* wfbase = (unsigned short*)(ws + 33904000);  // 6 x 32 KB
    float* psum  = (float*)(ws + 34100608);                // 128 KB
    unsigned int* pmax = (unsigned int*)(ws + 34231680);   // 128 KB
    int* gstart  = (int*)(ws + 34363776);                  // 2 KB
    int* flagp   = (int*)(ws + 34365824);
    unsigned short* w1t = (unsigned short*)(ws + 34366848); // 64 KB
    int* bcursor = (int*)(ws + 34432384);                  // padded: 196 x 64 B = 12.5 KB

    const size_t NEED = 34500000;
    if (ws_size < NEED) {
        unsigned int k = 0;
        while ((((size_t)1) << (k + 1)) <= ws_size && k < 62) k++;
        diag_kernel<<<1, 256, 0, stream>>>((unsigned short*)d_out,
                                           (unsigned short)(0x4000 | (k & 63)));
        return;
    }

    mega_pre_kernel<<<581, 256, 0, stream>>>(
        (const unsigned short*)d_in[0],
        d_in[3], d_in[5], d_in[7], d_in[9], d_in[11], d_in[13], wfbase,
        batch, gstart, psum, pmax, d_in[15], w1t, bcursor, flagp);

    // CSR build: scatter into fixed buckets, then per-bucket (dst, src-bucket) sort
    const int EB = (N_EDGES + 4095) / 4096;   // 196
    bscatter_kernel<<<EB, 1024, 0, stream>>>(srcv, dstv, bcursor, ebuf);
    bsort_kernel<<<NBUCK, 1024, 0, stream>>>(ebuf, bcursor, off, csr);

    const int GEMM_GRID = (N_NODES + 63) / 64;   // 782

    // layer 0: x -> A (fused gather_x + MLP0)
    fused_gin_kernel<64, false, true><<<GEMM_GRID, 256, 0, stream>>>(
        d_in[0], off, csr,
        wfbase + 0 * 16384, d_in[4], wfbase + 1 * 16384, d_in[6],
        A, N_NODES, flagp, batch, psum, pmax);

    // layer 1: A -> B (fused gather128 + MLP1)
    fused_gin_kernel<128, false, false><<<GEMM_GRID, 256, 0, stream>>>(
        A, off, csr,
        wfbase + 2 * 16384, d_in[8], wfbase + 3 * 16384, d_in[10],
        B, N_NODES, flagp, batch, psum, pmax);

    // layer 2: B -> pooled directly (fused gather128 + MLP2 + pool)
    fused_gin_kernel<128, true, false><<<GEMM_GRID, 256, 0, stream>>>(
        B, off, csr,
        wfbase + 4 * 16384, d_in[12], wfbase + 5 * 16384, d_in[14],
        A /*unused*/, N_NODES, flagp, batch, psum, pmax);

    // head
    head_kernel<<<NUM_GRAPHS, 128, 0, stream>>>(psum, pmax, gstart, w1t,
                                                d_in[16], d_in[17], d_in[18],
                                                d_out, flagp);
}